// Round 2
// baseline (233.221 us; speedup 1.0000x reference)
//
#include <hip/hip_runtime.h>
#include <hip/hip_bf16.h>

// Problem constants
#define BATCH 2
#define SEQ   2048
#define EMBD  1024
#define NHEAD 16
#define HDIM  64
#define QKV3  (3 * EMBD)   // 3072

// Q pre-scale folded into the QKV GEMM epilogue: (1/sqrt(HDIM)) * log2(e)
// so attention can use hardware exp2 directly (v_exp_f32 is 2^x).
#define QSCALE 0.18033688011112042f
// clamp for exp2 argument = 60 * log2(e)  (same guard as old exp clamp 60)
#define SCLAMP 86.56f

typedef __attribute__((ext_vector_type(8))) __bf16 bf16x8;
typedef __attribute__((ext_vector_type(4))) __bf16 bf16x4;
typedef __attribute__((ext_vector_type(4))) float f32x4;

__device__ __forceinline__ float fast_exp2(float x) {
#if __has_builtin(__builtin_amdgcn_exp2f)
    return __builtin_amdgcn_exp2f(x);
#else
    return exp2f(x);
#endif
}

// ---------------------------------------------------------------------------
// fp32 -> bf16 elementwise cast (8 elems/thread)
// ---------------------------------------------------------------------------
__global__ __launch_bounds__(256) void cast_f32_bf16(
    const float* __restrict__ in, __bf16* __restrict__ out)
{
    int i = (blockIdx.x * 256 + threadIdx.x) * 8;
    float4 a = *(const float4*)&in[i];
    float4 b = *(const float4*)&in[i + 4];
    bf16x8 o;
    o[0] = (__bf16)a.x; o[1] = (__bf16)a.y; o[2] = (__bf16)a.z; o[3] = (__bf16)a.w;
    o[4] = (__bf16)b.x; o[5] = (__bf16)b.y; o[6] = (__bf16)b.z; o[7] = (__bf16)b.w;
    *(bf16x8*)&out[i] = o;
}

// ---------------------------------------------------------------------------
// fp32 [K,N] -> bf16 [N,K] transpose+cast, 64x64 LDS tile, 256 threads
// ---------------------------------------------------------------------------
__global__ __launch_bounds__(256) void transpose_cast_bf16(
    const float* __restrict__ in, __bf16* __restrict__ out, int K, int N)
{
    __shared__ float t[64][65];
    const int k0 = blockIdx.y * 64, n0 = blockIdx.x * 64;
    const int tid = threadIdx.x;
    #pragma unroll
    for (int p = 0; p < 4; p++) {
        int kr = p * 16 + (tid >> 4);
        int c4 = (tid & 15) * 4;
        float4 v = *(const float4*)&in[(size_t)(k0 + kr) * N + n0 + c4];
        t[kr][c4] = v.x; t[kr][c4 + 1] = v.y; t[kr][c4 + 2] = v.z; t[kr][c4 + 3] = v.w;
    }
    __syncthreads();
    #pragma unroll
    for (int p = 0; p < 4; p++) {
        int nr = p * 16 + (tid >> 4);
        int k4 = (tid & 15) * 4;
        bf16x4 o;
        o[0] = (__bf16)t[k4 + 0][nr];
        o[1] = (__bf16)t[k4 + 1][nr];
        o[2] = (__bf16)t[k4 + 2][nr];
        o[3] = (__bf16)t[k4 + 3][nr];
        *(bf16x4*)&out[(size_t)(n0 + nr) * K + k0 + k4] = o;
    }
}

// ---------------------------------------------------------------------------
// bf16 V-transpose: qkv V region [k][d] per (b,h) -> vt[bh][d][k]
// ---------------------------------------------------------------------------
__global__ __launch_bounds__(256) void transpose_v_bf16(
    const __bf16* __restrict__ qkv, __bf16* __restrict__ vt)
{
    __shared__ __bf16 t[64][72];
    const int k0 = blockIdx.x * 64;
    const int bh = blockIdx.y;
    const int b = bh >> 4, h = bh & 15;
    const size_t base = (size_t)b * SEQ * QKV3 + 2 * EMBD + h * HDIM;
    const int tid = threadIdx.x;
    #pragma unroll
    for (int it = 0; it < 2; it++) {
        int flat = it * 256 + tid;      // 0..511
        int kr = flat >> 3;             // 0..63
        int d0 = (flat & 7) * 8;
        bf16x8 v = *(const bf16x8*)&qkv[base + (size_t)(k0 + kr) * QKV3 + d0];
        #pragma unroll
        for (int i = 0; i < 8; i++) t[kr][d0 + i] = v[i];
    }
    __syncthreads();
    #pragma unroll
    for (int it = 0; it < 2; it++) {
        int flat = it * 256 + tid;
        int d  = flat >> 3;             // 0..63
        int kc = (flat & 7) * 8;
        bf16x8 o;
        #pragma unroll
        for (int i = 0; i < 8; i++) o[i] = t[kc + i][d];
        *(bf16x8*)&vt[((size_t)bh * 64 + d) * SEQ + k0 + kc] = o;
    }
}

// ---------------------------------------------------------------------------
// bf16 MFMA GEMM (B^T form): C[M,N] = A[M,K] @ Bt[N,K]^T + bias[N]
// 128x128 block tile, 4 waves (2x2), mfma_f32_16x16x32_bf16, BK=32,
// global_load_lds width-16 staging. Columns < nscale get *QSCALE (folds the
// attention 1/sqrt(d) AND log2(e) into the Q region of the QKV projection).
// ---------------------------------------------------------------------------
template<bool OUT_BF16>
__global__ __launch_bounds__(256) void gemm_bt_mfma(
    const __bf16* __restrict__ A,   // [M,K]
    const __bf16* __restrict__ Bt,  // [N,K]
    const float* __restrict__ bias, // [N]
    void* __restrict__ Cv,          // [M,N]
    int M, int N, int K, int nscale)
{
    __shared__ __align__(16) __bf16 As[128 * 32];
    __shared__ __align__(16) __bf16 Bs[128 * 32];

    const int tid  = threadIdx.x;
    const int lane = tid & 63;
    const int wave = tid >> 6;
    const int wm = (wave >> 1) * 64;
    const int wn = (wave & 1) * 64;
    const int m0 = blockIdx.y * 128;
    const int n0 = blockIdx.x * 128;
    const int lm = lane & 15;
    const int kq = lane >> 4;

    f32x4 acc[4][4] = {};

    for (int k0 = 0; k0 < K; k0 += 32) {
        __syncthreads();
        #pragma unroll
        for (int r = 0; r < 2; r++) {
            int flat = r * 256 + tid;
            int row  = flat >> 2;
            int off  = (flat & 3) * 16;
            const char* ga = (const char*)(A + (size_t)(m0 + row) * K + k0) + off;
            char* la = (char*)As + flat * 16;
            __builtin_amdgcn_global_load_lds(
                (const __attribute__((address_space(1))) void*)ga,
                (__attribute__((address_space(3))) void*)la, 16, 0, 0);
            const char* gb = (const char*)(Bt + (size_t)(n0 + row) * K + k0) + off;
            char* lb = (char*)Bs + flat * 16;
            __builtin_amdgcn_global_load_lds(
                (const __attribute__((address_space(1))) void*)gb,
                (__attribute__((address_space(3))) void*)lb, 16, 0, 0);
        }
        __syncthreads();

        bf16x8 af[4], bf[4];
        #pragma unroll
        for (int t = 0; t < 4; t++) {
            af[t] = *(const bf16x8*)&As[(wm + t * 16 + lm) * 32 + kq * 8];
            bf[t] = *(const bf16x8*)&Bs[(wn + t * 16 + lm) * 32 + kq * 8];
        }
        #pragma unroll
        for (int i = 0; i < 4; i++)
            #pragma unroll
            for (int j = 0; j < 4; j++)
                acc[i][j] = __builtin_amdgcn_mfma_f32_16x16x32_bf16(
                    af[i], bf[j], acc[i][j], 0, 0, 0);
    }

    const int r0 = kq * 4;
    #pragma unroll
    for (int i = 0; i < 4; i++) {
        #pragma unroll
        for (int j = 0; j < 4; j++) {
            int col = n0 + wn + j * 16 + lm;
            float bv = bias[col];
            float sc = (col < nscale) ? QSCALE : 1.0f;
            #pragma unroll
            for (int r = 0; r < 4; r++) {
                int row = m0 + wm + i * 16 + r0 + r;
                float val = (acc[i][j][r] + bv) * sc;
                if (OUT_BF16) ((__bf16*)Cv)[(size_t)row * N + col] = (__bf16)val;
                else          ((float*)Cv)[(size_t)row * N + col] = val;
            }
        }
    }
}

// ---------------------------------------------------------------------------
// K-parallel MFMA flash attention (causal), bf16 in/out, fp32 accum.
// Block = 256 threads = 4 waves; block owns 32 q-rows (2 frags/wave).
// Wave w processes k-tiles t = w, w+4, ... INDEPENDENTLY (no barriers in the
// k-loop) accumulating private unnormalized (O, l).
//
// This round:
//  * XCD-aware block remap: 4 (b,h) pairs per XCD -> K/V working set 2 MB,
//    fits the 4 MB per-XCD L2; K/V loads become L2 hits instead of hammering
//    the shared L3 at ~5 TB/s. Heavy q-blocks first within each XCD.
//  * qf 4 -> 2 (32 q-rows/block): acc 32 AGPR + aq 16 VGPR + ~48 working
//    stays under the 128-reg occupancy cliff -> 4 waves/SIMD (was 2).
//    __launch_bounds__(256,4) pins the allocator to that budget.
//
// QK^T is computed SWAPPED: S^T = mfma(K_frag, Q_frag), so each lane holds
// P[q=c][k = jj*16 + quad*4 + r] — 4 CONSECUTIVE k of one q-row packed into
// one aligned 8-byte LDS store that lands exactly in the A-frag layout the
// PV readback needs (bank-uniform). Row-sums of l are lane-local + 2 shuffles.
// ---------------------------------------------------------------------------
__global__ __launch_bounds__(256, 4) void attn_kpar_mfma(
    const __bf16* __restrict__ qkv, const __bf16* __restrict__ vt,
    __bf16* __restrict__ attn)
{
    // smem: loop phase = Pbuf[4 waves][2 qf][2048 B] = 16384 B
    //       combine    = Ored[2][32][66] f32 (16896 B) + lred[2][32] (256 B)
    __shared__ __align__(16) char smem[17152];

    const int tid  = threadIdx.x;
    const int wave = tid >> 6;
    const int lane = tid & 63;
    const int quad = lane >> 4;
    const int c    = lane & 15;

    // XCD-aware remap: grid = (32 bh, 64 qblk) = 2048 blocks, 8 XCDs.
    // hw%8 = XCD (round-robin dispatch); give each XCD a contiguous logical
    // chunk of 256 blocks = 4 bh values. Within an XCD, qblk descends
    // (heaviest causal blocks first).
    const int hw = (int)(blockIdx.x + gridDim.x * blockIdx.y);
    const int logical = (hw & 7) * 256 + (hw >> 3);
    const int bh   = logical >> 6;          // 0..31 (4 per XCD)
    const int qblk = 63 - (logical & 63);   // 0..63, heavy first
    const int b  = bh >> 4;
    const int h  = bh & 15;
    const int q0 = qblk * 32;

    const size_t base = (size_t)b * SEQ * QKV3;
    const int hoff = h * HDIM;
    const __bf16* vbase = vt + (size_t)bh * 64 * SEQ;

    // Q B-frags (pre-scaled by log2(e)/8 in the QKV GEMM epilogue)
    bf16x8 aq[2][2];
    #pragma unroll
    for (int qf = 0; qf < 2; qf++) {
        const __bf16* qrow = qkv + base +
            (size_t)(q0 + qf * 16 + c) * QKV3 + hoff + quad * 8;
        aq[qf][0] = *(const bf16x8*)(qrow);
        aq[qf][1] = *(const bf16x8*)(qrow + 32);
    }

    f32x4 acc[2][4] = {};      // [qf][dd], C-layout: col=d (lane&15), row=q (quad*4+r)
    float lpart[2] = {};       // per-lane row-sum partial for q = c (per qf)

    char* pbw = smem + wave * 4096;
    const int ntiles = qblk / 2 + 1;    // 64-k tiles covering [0, q0+31]

    for (int t = wave; t < ntiles; t += 4) {
        const int k0 = t * 64;
        const bool diag = (t == ntiles - 1);

        // S^T = K Q^T per jj (16 k-rows), exp2, pack 4 bf16 -> one b64 store
        #pragma unroll
        for (int jj = 0; jj < 4; jj++) {
            const __bf16* krow = qkv + base +
                (size_t)(k0 + jj * 16 + c) * QKV3 + EMBD + hoff + quad * 8;
            bf16x8 bk0 = *(const bf16x8*)(krow);
            bf16x8 bk1 = *(const bf16x8*)(krow + 32);
            const int kb = k0 + jj * 16 + quad * 4;   // this lane's k base (4 r's)
            const int wb = (jj >> 1) * 1024 + (((jj & 1) * 2 + (quad >> 1))) * 256
                         + c * 16 + (quad & 1) * 8;
            #pragma unroll
            for (int qf = 0; qf < 2; qf++) {
                f32x4 s = {};
                s = __builtin_amdgcn_mfma_f32_16x16x32_bf16(bk0, aq[qf][0], s, 0, 0, 0);
                s = __builtin_amdgcn_mfma_f32_16x16x32_bf16(bk1, aq[qf][1], s, 0, 0, 0);
                const int qa = q0 + qf * 16 + c;
                bf16x4 pk;
                #pragma unroll
                for (int r = 0; r < 4; r++) {
                    float p;
                    if (diag && (kb + r > qa)) p = 0.f;
                    else p = fast_exp2(fminf(s[r], SCLAMP));
                    lpart[qf] += p;
                    pk[r] = (__bf16)p;
                }
                *(bf16x4*)(pbw + qf * 2048 + wb) = pk;
            }
        }

        // O += P V : P A-frags from wave-private LDS (in-order per-wave pipe),
        // V^T B-frags direct from vt (L2-resident after the XCD remap).
        __builtin_amdgcn_s_setprio(1);
        #pragma unroll
        for (int kc = 0; kc < 2; kc++) {
            bf16x8 ap[2];
            #pragma unroll
            for (int qf = 0; qf < 2; qf++)
                ap[qf] = *(const bf16x8*)(pbw + qf * 2048 + kc * 1024 + lane * 16);
            #pragma unroll
            for (int dd = 0; dd < 4; dd++) {
                const __bf16* vr = vbase + (size_t)(dd * 16 + c) * SEQ
                                 + k0 + kc * 32 + quad * 8;
                bf16x8 bv = *(const bf16x8*)(vr);
                #pragma unroll
                for (int qf = 0; qf < 2; qf++)
                    acc[qf][dd] = __builtin_amdgcn_mfma_f32_16x16x32_bf16(
                        ap[qf], bv, acc[qf][dd], 0, 0, 0);
            }
        }
        __builtin_amdgcn_s_setprio(0);
    }

    // Full row-sums of l within wave: lane holds q=c partial; reduce across quads
    #pragma unroll
    for (int qf = 0; qf < 2; qf++) {
        float v = lpart[qf];
        v += __shfl_xor(v, 16);
        v += __shfl_xor(v, 32);
        lpart[qf] = v;
    }

    __syncthreads();   // done with Pbuf; reuse smem for the combine

    float* Ored = (float*)smem;                    // [2][32][66]
    float* lred = (float*)(smem + 16896);          // [2][32]

    if (wave < 2) {
        float* R = Ored + wave * (32 * 66);
        #pragma unroll
        for (int qf = 0; qf < 2; qf++) {
            #pragma unroll
            for (int dd = 0; dd < 4; dd++)
                #pragma unroll
                for (int r = 0; r < 4; r++)
                    R[(qf * 16 + quad * 4 + r) * 66 + dd * 16 + c] = acc[qf][dd][r];
            if (quad == 0) lred[wave * 32 + qf * 16 + c] = lpart[qf];
        }
    }
    __syncthreads();
    if (wave >= 2) {
        float* R = Ored + (wave - 2) * (32 * 66);
        #pragma unroll
        for (int qf = 0; qf < 2; qf++) {
            #pragma unroll
            for (int dd = 0; dd < 4; dd++)
                #pragma unroll
                for (int r = 0; r < 4; r++)
                    R[(qf * 16 + quad * 4 + r) * 66 + dd * 16 + c] += acc[qf][dd][r];
            if (quad == 0) lred[(wave - 2) * 32 + qf * 16 + c] += lpart[qf];
        }
    }
    __syncthreads();

    // Final: 256 threads, each one 8-col chunk of one row
    {
        const int row = tid >> 3;          // 0..31
        const int cg  = tid & 7;           // 8-col group
        const float l = lred[row] + lred[32 + row];
        const float inv = 1.f / l;
        const float* R0 = Ored + row * 66 + cg * 8;
        const float* R1 = R0 + 32 * 66;
        bf16x8 o;
        #pragma unroll
        for (int i = 0; i < 8; i++) o[i] = (__bf16)((R0[i] + R1[i]) * inv);
        *(bf16x8*)&attn[((size_t)b * SEQ + q0 + row) * EMBD + hoff + cg * 8] = o;
    }
}

// ---------------------------------------------------------------------------
extern "C" void kernel_launch(void* const* d_in, const int* in_sizes, int n_in,
                              void* d_out, int out_size, void* d_ws, size_t ws_size,
                              hipStream_t stream)
{
    const float* x     = (const float*)d_in[0];  // [2,2048,1024]
    const float* W_qkv = (const float*)d_in[1];  // [1024,3072]
    const float* b_qkv = (const float*)d_in[2];  // [3072]
    const float* W_out = (const float*)d_in[3];  // [1024,1024]
    const float* b_out = (const float*)d_in[4];  // [1024]
    float* out = (float*)d_out;                  // [2,2048,1024] fp32

    const int M = BATCH * SEQ;   // 4096

    __bf16* xbf    = (__bf16*)d_ws;                          // [4096,1024]  8 MB
    __bf16* Wqkv_t = xbf    + (size_t)M * EMBD;              // [3072,1024]  6 MB
    __bf16* Wout_t = Wqkv_t + (size_t)QKV3 * EMBD;           // [1024,1024]  2 MB
    __bf16* qkv    = Wout_t + (size_t)EMBD * EMBD;           // [4096,3072] 24 MB
    __bf16* attn   = qkv    + (size_t)M * QKV3;              // [4096,1024]  8 MB
    __bf16* vtbuf  = attn   + (size_t)M * EMBD;              // [32,64,2048]  8 MB

    // 0) Casts
    cast_f32_bf16<<<(M * EMBD) / (256 * 8), 256, 0, stream>>>(x, xbf);
    {
        dim3 g(QKV3 / 64, EMBD / 64);
        transpose_cast_bf16<<<g, 256, 0, stream>>>(W_qkv, Wqkv_t, EMBD, QKV3);
    }
    {
        dim3 g(EMBD / 64, EMBD / 64);
        transpose_cast_bf16<<<g, 256, 0, stream>>>(W_out, Wout_t, EMBD, EMBD);
    }
    // 1) QKV projection (bf16 out; Q columns pre-scaled by log2(e)/8)
    {
        dim3 grid(QKV3 / 128, M / 128);
        gemm_bt_mfma<true><<<grid, 256, 0, stream>>>(xbf, Wqkv_t, b_qkv, qkv, M, QKV3, EMBD, EMBD);
    }
    // 1b) Pre-transpose V to [bh][d][k]
    {
        dim3 grid(SEQ / 64, BATCH * NHEAD);
        transpose_v_bf16<<<grid, 256, 0, stream>>>(qkv, vtbuf);
    }
    // 2) K-parallel MFMA flash causal attention (32 q/block, XCD-clustered)
    {
        dim3 grid(BATCH * NHEAD, SEQ / 32);
        attn_kpar_mfma<<<grid, 256, 0, stream>>>(qkv, vtbuf, attn);
    }
    // 3) Output projection (fp32 out)
    {
        dim3 grid(EMBD / 128, M / 128);
        gemm_bt_mfma<false><<<grid, 256, 0, stream>>>(attn, Wout_t, b_out, out, M, EMBD, EMBD, 0);
    }
}

// Round 3
// 205.095 us; speedup vs baseline: 1.1371x; 1.1371x over previous
//
#include <hip/hip_runtime.h>
#include <hip/hip_bf16.h>

// Problem constants
#define BATCH 2
#define SEQ   2048
#define EMBD  1024
#define NHEAD 16
#define HDIM  64
#define QKV3  (3 * EMBD)   // 3072

// Q pre-scale folded into the QKV GEMM epilogue: (1/sqrt(HDIM)) * log2(e)
// so attention can use hardware exp2 directly (v_exp_f32 is 2^x).
#define QSCALE 0.18033688011112042f
// clamp for exp2 argument = 60 * log2(e)  (same guard as old exp clamp 60)
#define SCLAMP 86.56f

typedef __attribute__((ext_vector_type(8))) __bf16 bf16x8;
typedef __attribute__((ext_vector_type(4))) __bf16 bf16x4;
typedef __attribute__((ext_vector_type(4))) float f32x4;

__device__ __forceinline__ float fast_exp2(float x) {
#if __has_builtin(__builtin_amdgcn_exp2f)
    return __builtin_amdgcn_exp2f(x);
#else
    return exp2f(x);
#endif
}

// ---------------------------------------------------------------------------
// fp32 -> bf16 elementwise cast (8 elems/thread)
// ---------------------------------------------------------------------------
__global__ __launch_bounds__(256) void cast_f32_bf16(
    const float* __restrict__ in, __bf16* __restrict__ out)
{
    int i = (blockIdx.x * 256 + threadIdx.x) * 8;
    float4 a = *(const float4*)&in[i];
    float4 b = *(const float4*)&in[i + 4];
    bf16x8 o;
    o[0] = (__bf16)a.x; o[1] = (__bf16)a.y; o[2] = (__bf16)a.z; o[3] = (__bf16)a.w;
    o[4] = (__bf16)b.x; o[5] = (__bf16)b.y; o[6] = (__bf16)b.z; o[7] = (__bf16)b.w;
    *(bf16x8*)&out[i] = o;
}

// ---------------------------------------------------------------------------
// fp32 [K,N] -> bf16 [N,K] transpose+cast, 64x64 LDS tile, 256 threads
// ---------------------------------------------------------------------------
__global__ __launch_bounds__(256) void transpose_cast_bf16(
    const float* __restrict__ in, __bf16* __restrict__ out, int K, int N)
{
    __shared__ float t[64][65];
    const int k0 = blockIdx.y * 64, n0 = blockIdx.x * 64;
    const int tid = threadIdx.x;
    #pragma unroll
    for (int p = 0; p < 4; p++) {
        int kr = p * 16 + (tid >> 4);
        int c4 = (tid & 15) * 4;
        float4 v = *(const float4*)&in[(size_t)(k0 + kr) * N + n0 + c4];
        t[kr][c4] = v.x; t[kr][c4 + 1] = v.y; t[kr][c4 + 2] = v.z; t[kr][c4 + 3] = v.w;
    }
    __syncthreads();
    #pragma unroll
    for (int p = 0; p < 4; p++) {
        int nr = p * 16 + (tid >> 4);
        int k4 = (tid & 15) * 4;
        bf16x4 o;
        o[0] = (__bf16)t[k4 + 0][nr];
        o[1] = (__bf16)t[k4 + 1][nr];
        o[2] = (__bf16)t[k4 + 2][nr];
        o[3] = (__bf16)t[k4 + 3][nr];
        *(bf16x4*)&out[(size_t)(n0 + nr) * K + k0 + k4] = o;
    }
}

// ---------------------------------------------------------------------------
// bf16 V-transpose: qkv V region [k][d] per (b,h) -> vt[bh][d][k]
// ---------------------------------------------------------------------------
__global__ __launch_bounds__(256) void transpose_v_bf16(
    const __bf16* __restrict__ qkv, __bf16* __restrict__ vt)
{
    __shared__ __bf16 t[64][72];
    const int k0 = blockIdx.x * 64;
    const int bh = blockIdx.y;
    const int b = bh >> 4, h = bh & 15;
    const size_t base = (size_t)b * SEQ * QKV3 + 2 * EMBD + h * HDIM;
    const int tid = threadIdx.x;
    #pragma unroll
    for (int it = 0; it < 2; it++) {
        int flat = it * 256 + tid;      // 0..511
        int kr = flat >> 3;             // 0..63
        int d0 = (flat & 7) * 8;
        bf16x8 v = *(const bf16x8*)&qkv[base + (size_t)(k0 + kr) * QKV3 + d0];
        #pragma unroll
        for (int i = 0; i < 8; i++) t[kr][d0 + i] = v[i];
    }
    __syncthreads();
    #pragma unroll
    for (int it = 0; it < 2; it++) {
        int flat = it * 256 + tid;
        int d  = flat >> 3;             // 0..63
        int kc = (flat & 7) * 8;
        bf16x8 o;
        #pragma unroll
        for (int i = 0; i < 8; i++) o[i] = t[kc + i][d];
        *(bf16x8*)&vt[((size_t)bh * 64 + d) * SEQ + k0 + kc] = o;
    }
}

// ---------------------------------------------------------------------------
// bf16 MFMA GEMM (B^T form): C[M,N] = A[M,K] @ Bt[N,K]^T + bias[N]
// 128x128 block tile, 4 waves (2x2), mfma_f32_16x16x32_bf16, BK=32,
// global_load_lds width-16 staging. Columns < nscale get *QSCALE (folds the
// attention 1/sqrt(d) AND log2(e) into the Q region of the QKV projection).
// ---------------------------------------------------------------------------
template<bool OUT_BF16>
__global__ __launch_bounds__(256) void gemm_bt_mfma(
    const __bf16* __restrict__ A,   // [M,K]
    const __bf16* __restrict__ Bt,  // [N,K]
    const float* __restrict__ bias, // [N]
    void* __restrict__ Cv,          // [M,N]
    int M, int N, int K, int nscale)
{
    __shared__ __align__(16) __bf16 As[128 * 32];
    __shared__ __align__(16) __bf16 Bs[128 * 32];

    const int tid  = threadIdx.x;
    const int lane = tid & 63;
    const int wave = tid >> 6;
    const int wm = (wave >> 1) * 64;
    const int wn = (wave & 1) * 64;
    const int m0 = blockIdx.y * 128;
    const int n0 = blockIdx.x * 128;
    const int lm = lane & 15;
    const int kq = lane >> 4;

    f32x4 acc[4][4] = {};

    for (int k0 = 0; k0 < K; k0 += 32) {
        __syncthreads();
        #pragma unroll
        for (int r = 0; r < 2; r++) {
            int flat = r * 256 + tid;
            int row  = flat >> 2;
            int off  = (flat & 3) * 16;
            const char* ga = (const char*)(A + (size_t)(m0 + row) * K + k0) + off;
            char* la = (char*)As + flat * 16;
            __builtin_amdgcn_global_load_lds(
                (const __attribute__((address_space(1))) void*)ga,
                (__attribute__((address_space(3))) void*)la, 16, 0, 0);
            const char* gb = (const char*)(Bt + (size_t)(n0 + row) * K + k0) + off;
            char* lb = (char*)Bs + flat * 16;
            __builtin_amdgcn_global_load_lds(
                (const __attribute__((address_space(1))) void*)gb,
                (__attribute__((address_space(3))) void*)lb, 16, 0, 0);
        }
        __syncthreads();

        bf16x8 af[4], bf[4];
        #pragma unroll
        for (int t = 0; t < 4; t++) {
            af[t] = *(const bf16x8*)&As[(wm + t * 16 + lm) * 32 + kq * 8];
            bf[t] = *(const bf16x8*)&Bs[(wn + t * 16 + lm) * 32 + kq * 8];
        }
        #pragma unroll
        for (int i = 0; i < 4; i++)
            #pragma unroll
            for (int j = 0; j < 4; j++)
                acc[i][j] = __builtin_amdgcn_mfma_f32_16x16x32_bf16(
                    af[i], bf[j], acc[i][j], 0, 0, 0);
    }

    const int r0 = kq * 4;
    #pragma unroll
    for (int i = 0; i < 4; i++) {
        #pragma unroll
        for (int j = 0; j < 4; j++) {
            int col = n0 + wn + j * 16 + lm;
            float bv = bias[col];
            float sc = (col < nscale) ? QSCALE : 1.0f;
            #pragma unroll
            for (int r = 0; r < 4; r++) {
                int row = m0 + wm + i * 16 + r0 + r;
                float val = (acc[i][j][r] + bv) * sc;
                if (OUT_BF16) ((__bf16*)Cv)[(size_t)row * N + col] = (__bf16)val;
                else          ((float*)Cv)[(size_t)row * N + col] = val;
            }
        }
    }
}

// ---------------------------------------------------------------------------
// K-parallel MFMA flash attention (causal), bf16 in/out, fp32 accum.
// Block = 256 threads = 4 waves; block owns 64 q-rows (4 frags/wave).
// Wave w processes k-tiles t = w, w+4, ... INDEPENDENTLY (no barriers in the
// k-loop) accumulating private unnormalized (O, l).
//
// Round-3 structure = round-1 geometry (QBLK=64, qf=4: best measured) plus:
//  * XCD-aware block remap (kept from r2 — per-tile time improved 20%):
//    4 (b,h) pairs per XCD -> K/V working set 2 MB fits the 4 MB per-XCD L2.
//  * T14 async-split register pipeline: V B-frags prefetched at tile top
//    (consumed ~600cy later in PV, latency hidden under QK+exp); K A-frags
//    prefetched one tile ahead (issued during exp/PV of the previous tile).
//    Removes global-load latency from the per-tile serial chain — the
//    measured bottleneck (126K cy/CU vs ~64K cy of issue work in r1).
//
// QK^T is computed SWAPPED: S^T = mfma(K_frag, Q_frag), so each lane holds
// P[q=c][k = jj*16 + quad*4 + r] — 4 CONSECUTIVE k of one q-row packed into
// one aligned 8-byte LDS store that lands exactly in the A-frag layout the
// PV readback needs (bank-uniform). Row-sums of l are lane-local + 2 shuffles.
// End: 3-barrier LDS tree combine of the 4 waves' partials, then normalize.
// ---------------------------------------------------------------------------
__global__ __launch_bounds__(256) void attn_kpar_mfma(
    const __bf16* __restrict__ qkv, const __bf16* __restrict__ vt,
    __bf16* __restrict__ attn)
{
    // smem: loop phase = Pbuf[4 waves][4 qf][2048 B] = 32768 B
    //       combine    = Ored[2][64][66] f32 (33792 B) + lred[2][64] (512 B)
    __shared__ __align__(16) char smem[34304];

    const int tid  = threadIdx.x;
    const int wave = tid >> 6;
    const int lane = tid & 63;
    const int quad = lane >> 4;
    const int c    = lane & 15;

    // XCD-aware remap: grid = 32 bh x 32 qblk = 1024 blocks, 8 XCDs.
    // hw%8 = XCD (round-robin dispatch); each XCD gets a contiguous logical
    // chunk of 128 blocks = 4 bh values (K/V 4 x 512 KB = 2 MB < L2).
    // Within an XCD, qblk descends (heaviest causal blocks first).
    const int hw = (int)(blockIdx.x + gridDim.x * blockIdx.y);
    const int logical = (hw & 7) * 128 + (hw >> 3);
    const int bh   = logical >> 5;          // 0..31 (4 per XCD)
    const int qblk = 31 - (logical & 31);   // 0..31, heavy first
    const int b  = bh >> 4;
    const int h  = bh & 15;
    const int q0 = qblk * 64;

    const size_t base = (size_t)b * SEQ * QKV3;
    const int hoff = h * HDIM;
    const __bf16* vbase = vt + (size_t)bh * 64 * SEQ;

    // Q B-frags (pre-scaled by log2(e)/8 in the QKV GEMM epilogue)
    bf16x8 aq[4][2];
    #pragma unroll
    for (int qf = 0; qf < 4; qf++) {
        const __bf16* qrow = qkv + base +
            (size_t)(q0 + qf * 16 + c) * QKV3 + hoff + quad * 8;
        aq[qf][0] = *(const bf16x8*)(qrow);
        aq[qf][1] = *(const bf16x8*)(qrow + 32);
    }

    f32x4 acc[4][4] = {};      // [qf][dd], C-layout: col=d (lane&15), row=q (quad*4+r)
    float lpart[4] = {};       // per-lane row-sum partial for q = c (per qf)

    char* pbw = smem + wave * 8192;
    const int ntiles = qblk + 1;    // 64-k tiles covering [0, q0+63]

    // Prologue: K A-frags for this wave's first tile (t = wave).
    // Safe even for idle waves: k0p <= 192 < SEQ, reads land in valid qkv.
    bf16x8 kreg[4][2];
    {
        const int k0p = wave * 64;
        #pragma unroll
        for (int jj = 0; jj < 4; jj++) {
            const __bf16* krow = qkv + base +
                (size_t)(k0p + jj * 16 + c) * QKV3 + EMBD + hoff + quad * 8;
            kreg[jj][0] = *(const bf16x8*)(krow);
            kreg[jj][1] = *(const bf16x8*)(krow + 32);
        }
    }

    for (int t = wave; t < ntiles; t += 4) {
        const int k0 = t * 64;
        const bool diag = (t == ntiles - 1);

        // V prefetch for THIS tile: independent of P; latency hides under
        // the QK + exp + pack phase (~600 cy).
        bf16x8 vreg[2][4];
        #pragma unroll
        for (int kc = 0; kc < 2; kc++)
            #pragma unroll
            for (int dd = 0; dd < 4; dd++)
                vreg[kc][dd] = *(const bf16x8*)(vbase
                    + (size_t)(dd * 16 + c) * SEQ + k0 + kc * 32 + quad * 8);

        // S^T = K Q^T per jj (16 k-rows) from prefetched kreg; exp2; pack
        // 4 bf16 -> one b64 LDS store in the PV A-frag layout.
        #pragma unroll
        for (int jj = 0; jj < 4; jj++) {
            const int kb = k0 + jj * 16 + quad * 4;   // this lane's k base
            const int wb = (jj >> 1) * 1024 + (((jj & 1) * 2 + (quad >> 1))) * 256
                         + c * 16 + (quad & 1) * 8;
            #pragma unroll
            for (int qf = 0; qf < 4; qf++) {
                f32x4 s = {};
                s = __builtin_amdgcn_mfma_f32_16x16x32_bf16(kreg[jj][0], aq[qf][0], s, 0, 0, 0);
                s = __builtin_amdgcn_mfma_f32_16x16x32_bf16(kreg[jj][1], aq[qf][1], s, 0, 0, 0);
                const int qa = q0 + qf * 16 + c;
                bf16x4 pk;
                #pragma unroll
                for (int r = 0; r < 4; r++) {
                    float p;
                    if (diag && (kb + r > qa)) p = 0.f;
                    else p = fast_exp2(fminf(s[r], SCLAMP));
                    lpart[qf] += p;
                    pk[r] = (__bf16)p;
                }
                *(bf16x4*)(pbw + qf * 2048 + wb) = pk;
            }
        }

        // K prefetch for the NEXT tile of this wave (t+4): issued now so its
        // latency hides under the PV phase + loop turn.
        if (t + 4 < ntiles) {
            const int k0n = k0 + 256;
            #pragma unroll
            for (int jj = 0; jj < 4; jj++) {
                const __bf16* krow = qkv + base +
                    (size_t)(k0n + jj * 16 + c) * QKV3 + EMBD + hoff + quad * 8;
                kreg[jj][0] = *(const bf16x8*)(krow);
                kreg[jj][1] = *(const bf16x8*)(krow + 32);
            }
        }

        // O += P V : P A-frags from wave-private LDS (in-order per-wave pipe),
        // V^T B-frags from the prefetched vreg.
        __builtin_amdgcn_s_setprio(1);
        #pragma unroll
        for (int kc = 0; kc < 2; kc++) {
            bf16x8 ap[4];
            #pragma unroll
            for (int qf = 0; qf < 4; qf++)
                ap[qf] = *(const bf16x8*)(pbw + qf * 2048 + kc * 1024 + lane * 16);
            #pragma unroll
            for (int dd = 0; dd < 4; dd++) {
                #pragma unroll
                for (int qf = 0; qf < 4; qf++)
                    acc[qf][dd] = __builtin_amdgcn_mfma_f32_16x16x32_bf16(
                        ap[qf], vreg[kc][dd], acc[qf][dd], 0, 0, 0);
            }
        }
        __builtin_amdgcn_s_setprio(0);
    }

    // Full row-sums of l within wave: lane holds q=c partial; reduce across quads
    #pragma unroll
    for (int qf = 0; qf < 4; qf++) {
        float v = lpart[qf];
        v += __shfl_xor(v, 16);
        v += __shfl_xor(v, 32);
        lpart[qf] = v;
    }

    __syncthreads();   // done with Pbuf; reuse smem for the combine

    float* Ored = (float*)smem;                    // [2][64][66]
    float* lred = (float*)(smem + 33792);          // [2][64]

    if (wave < 2) {
        float* R = Ored + wave * (64 * 66);
        #pragma unroll
        for (int qf = 0; qf < 4; qf++) {
            #pragma unroll
            for (int dd = 0; dd < 4; dd++)
                #pragma unroll
                for (int r = 0; r < 4; r++)
                    R[(qf * 16 + quad * 4 + r) * 66 + dd * 16 + c] = acc[qf][dd][r];
            if (quad == 0) lred[wave * 64 + qf * 16 + c] = lpart[qf];
        }
    }
    __syncthreads();
    if (wave >= 2) {
        float* R = Ored + (wave - 2) * (64 * 66);
        #pragma unroll
        for (int qf = 0; qf < 4; qf++) {
            #pragma unroll
            for (int dd = 0; dd < 4; dd++)
                #pragma unroll
                for (int r = 0; r < 4; r++)
                    R[(qf * 16 + quad * 4 + r) * 66 + dd * 16 + c] += acc[qf][dd][r];
            if (quad == 0) lred[(wave - 2) * 64 + qf * 16 + c] += lpart[qf];
        }
    }
    __syncthreads();

    // Final: each thread does one 8-col chunk of one row; 2 iterations for 64 rows
    #pragma unroll
    for (int it = 0; it < 2; it++) {
        const int flat = it * 256 + tid;
        const int row = flat >> 3;         // 0..63
        const int cg  = flat & 7;          // 8-col group
        const float l = lred[row] + lred[64 + row];
        const float inv = 1.f / l;
        const float* R0 = Ored + row * 66 + cg * 8;
        const float* R1 = R0 + 64 * 66;
        bf16x8 o;
        #pragma unroll
        for (int i = 0; i < 8; i++) o[i] = (__bf16)((R0[i] + R1[i]) * inv);
        *(bf16x8*)&attn[((size_t)b * SEQ + q0 + row) * EMBD + hoff + cg * 8] = o;
    }
}

// ---------------------------------------------------------------------------
extern "C" void kernel_launch(void* const* d_in, const int* in_sizes, int n_in,
                              void* d_out, int out_size, void* d_ws, size_t ws_size,
                              hipStream_t stream)
{
    const float* x     = (const float*)d_in[0];  // [2,2048,1024]
    const float* W_qkv = (const float*)d_in[1];  // [1024,3072]
    const float* b_qkv = (const float*)d_in[2];  // [3072]
    const float* W_out = (const float*)d_in[3];  // [1024,1024]
    const float* b_out = (const float*)d_in[4];  // [1024]
    float* out = (float*)d_out;                  // [2,2048,1024] fp32

    const int M = BATCH * SEQ;   // 4096

    __bf16* xbf    = (__bf16*)d_ws;                          // [4096,1024]  8 MB
    __bf16* Wqkv_t = xbf    + (size_t)M * EMBD;              // [3072,1024]  6 MB
    __bf16* Wout_t = Wqkv_t + (size_t)QKV3 * EMBD;           // [1024,1024]  2 MB
    __bf16* qkv    = Wout_t + (size_t)EMBD * EMBD;           // [4096,3072] 24 MB
    __bf16* attn   = qkv    + (size_t)M * QKV3;              // [4096,1024]  8 MB
    __bf16* vtbuf  = attn   + (size_t)M * EMBD;              // [32,64,2048]  8 MB

    // 0) Casts
    cast_f32_bf16<<<(M * EMBD) / (256 * 8), 256, 0, stream>>>(x, xbf);
    {
        dim3 g(QKV3 / 64, EMBD / 64);
        transpose_cast_bf16<<<g, 256, 0, stream>>>(W_qkv, Wqkv_t, EMBD, QKV3);
    }
    {
        dim3 g(EMBD / 64, EMBD / 64);
        transpose_cast_bf16<<<g, 256, 0, stream>>>(W_out, Wout_t, EMBD, EMBD);
    }
    // 1) QKV projection (bf16 out; Q columns pre-scaled by log2(e)/8)
    {
        dim3 grid(QKV3 / 128, M / 128);
        gemm_bt_mfma<true><<<grid, 256, 0, stream>>>(xbf, Wqkv_t, b_qkv, qkv, M, QKV3, EMBD, EMBD);
    }
    // 1b) Pre-transpose V to [bh][d][k]
    {
        dim3 grid(SEQ / 64, BATCH * NHEAD);
        transpose_v_bf16<<<grid, 256, 0, stream>>>(qkv, vtbuf);
    }
    // 2) K-parallel MFMA flash causal attention (64 q/block, XCD-clustered,
    //    K/V register-prefetch pipeline)
    {
        dim3 grid(BATCH * NHEAD, SEQ / 64);
        attn_kpar_mfma<<<grid, 256, 0, stream>>>(qkv, vtbuf, attn);
    }
    // 3) Output projection (fp32 out)
    {
        dim3 grid(EMBD / 128, M / 128);
        gemm_bt_mfma<false><<<grid, 256, 0, stream>>>(attn, Wout_t, b_out, out, M, EMBD, EMBD, 0);
    }
}

// Round 4
// 204.154 us; speedup vs baseline: 1.1424x; 1.0046x over previous
//
#include <hip/hip_runtime.h>
#include <hip/hip_bf16.h>

// Problem constants
#define BATCH 2
#define SEQ   2048
#define EMBD  1024
#define NHEAD 16
#define HDIM  64
#define QKV3  (3 * EMBD)   // 3072

// Q pre-scale folded into the QKV GEMM epilogue: (1/sqrt(HDIM)) * log2(e)
// so attention can use hardware exp2 directly (v_exp_f32 is 2^x).
#define QSCALE 0.18033688011112042f
// clamp for exp2 argument = 60 * log2(e)  (same guard as old exp clamp 60)
#define SCLAMP 86.56f

typedef __attribute__((ext_vector_type(8)))  __bf16 bf16x8;
typedef __attribute__((ext_vector_type(4)))  __bf16 bf16x4;
typedef __attribute__((ext_vector_type(4)))  float  f32x4;
typedef __attribute__((ext_vector_type(16))) float  f32x16;
typedef __attribute__((ext_vector_type(4)))  unsigned int u32x4;

__device__ __forceinline__ float fast_exp2(float x) {
#if __has_builtin(__builtin_amdgcn_exp2f)
    return __builtin_amdgcn_exp2f(x);
#else
    return exp2f(x);
#endif
}

// pack two f32 -> one dword of 2 bf16 (lo = a, hi = b); no builtin on gfx950
__device__ __forceinline__ unsigned pk_bf16(float a, float b) {
    unsigned d;
    asm("v_cvt_pk_bf16_f32 %0, %1, %2" : "=v"(d) : "v"(a), "v"(b));
    return d;
}

// v_permlane32_swap_b32: new a[32:63] = old b[0:31], new b[0:31] = old a[32:63]
__device__ __forceinline__ void pl32_swap(unsigned &a, unsigned &b) {
    asm volatile("v_permlane32_swap_b32 %0, %1" : "+v"(a), "+v"(b));
}

__device__ __forceinline__ bf16x8 frag4(unsigned a, unsigned b, unsigned c, unsigned d) {
    u32x4 u = {a, b, c, d};
    return __builtin_bit_cast(bf16x8, u);
}

// ---------------------------------------------------------------------------
// fp32 -> bf16 elementwise cast (8 elems/thread)
// ---------------------------------------------------------------------------
__global__ __launch_bounds__(256) void cast_f32_bf16(
    const float* __restrict__ in, __bf16* __restrict__ out)
{
    int i = (blockIdx.x * 256 + threadIdx.x) * 8;
    float4 a = *(const float4*)&in[i];
    float4 b = *(const float4*)&in[i + 4];
    bf16x8 o;
    o[0] = (__bf16)a.x; o[1] = (__bf16)a.y; o[2] = (__bf16)a.z; o[3] = (__bf16)a.w;
    o[4] = (__bf16)b.x; o[5] = (__bf16)b.y; o[6] = (__bf16)b.z; o[7] = (__bf16)b.w;
    *(bf16x8*)&out[i] = o;
}

// ---------------------------------------------------------------------------
// fp32 [K,N] -> bf16 [N,K] transpose+cast, 64x64 LDS tile, 256 threads
// ---------------------------------------------------------------------------
__global__ __launch_bounds__(256) void transpose_cast_bf16(
    const float* __restrict__ in, __bf16* __restrict__ out, int K, int N)
{
    __shared__ float t[64][65];
    const int k0 = blockIdx.y * 64, n0 = blockIdx.x * 64;
    const int tid = threadIdx.x;
    #pragma unroll
    for (int p = 0; p < 4; p++) {
        int kr = p * 16 + (tid >> 4);
        int c4 = (tid & 15) * 4;
        float4 v = *(const float4*)&in[(size_t)(k0 + kr) * N + n0 + c4];
        t[kr][c4] = v.x; t[kr][c4 + 1] = v.y; t[kr][c4 + 2] = v.z; t[kr][c4 + 3] = v.w;
    }
    __syncthreads();
    #pragma unroll
    for (int p = 0; p < 4; p++) {
        int nr = p * 16 + (tid >> 4);
        int k4 = (tid & 15) * 4;
        bf16x4 o;
        o[0] = (__bf16)t[k4 + 0][nr];
        o[1] = (__bf16)t[k4 + 1][nr];
        o[2] = (__bf16)t[k4 + 2][nr];
        o[3] = (__bf16)t[k4 + 3][nr];
        *(bf16x4*)&out[(size_t)(n0 + nr) * K + k0 + k4] = o;
    }
}

// ---------------------------------------------------------------------------
// bf16 V-transpose: qkv V region [k][d] per (b,h) -> vt[bh][d][k]
// ---------------------------------------------------------------------------
__global__ __launch_bounds__(256) void transpose_v_bf16(
    const __bf16* __restrict__ qkv, __bf16* __restrict__ vt)
{
    __shared__ __bf16 t[64][72];
    const int k0 = blockIdx.x * 64;
    const int bh = blockIdx.y;
    const int b = bh >> 4, h = bh & 15;
    const size_t base = (size_t)b * SEQ * QKV3 + 2 * EMBD + h * HDIM;
    const int tid = threadIdx.x;
    #pragma unroll
    for (int it = 0; it < 2; it++) {
        int flat = it * 256 + tid;      // 0..511
        int kr = flat >> 3;             // 0..63
        int d0 = (flat & 7) * 8;
        bf16x8 v = *(const bf16x8*)&qkv[base + (size_t)(k0 + kr) * QKV3 + d0];
        #pragma unroll
        for (int i = 0; i < 8; i++) t[kr][d0 + i] = v[i];
    }
    __syncthreads();
    #pragma unroll
    for (int it = 0; it < 2; it++) {
        int flat = it * 256 + tid;
        int d  = flat >> 3;             // 0..63
        int kc = (flat & 7) * 8;
        bf16x8 o;
        #pragma unroll
        for (int i = 0; i < 8; i++) o[i] = t[kc + i][d];
        *(bf16x8*)&vt[((size_t)bh * 64 + d) * SEQ + k0 + kc] = o;
    }
}

// ---------------------------------------------------------------------------
// bf16 MFMA GEMM (B^T form): C[M,N] = A[M,K] @ Bt[N,K]^T + bias[N]
// 128x128 block tile, 4 waves (2x2), mfma_f32_16x16x32_bf16, BK=32,
// global_load_lds width-16 staging. Columns < nscale get *QSCALE (folds the
// attention 1/sqrt(d) AND log2(e) into the Q region of the QKV projection).
// ---------------------------------------------------------------------------
template<bool OUT_BF16>
__global__ __launch_bounds__(256) void gemm_bt_mfma(
    const __bf16* __restrict__ A,   // [M,K]
    const __bf16* __restrict__ Bt,  // [N,K]
    const float* __restrict__ bias, // [N]
    void* __restrict__ Cv,          // [M,N]
    int M, int N, int K, int nscale)
{
    __shared__ __align__(16) __bf16 As[128 * 32];
    __shared__ __align__(16) __bf16 Bs[128 * 32];

    const int tid  = threadIdx.x;
    const int lane = tid & 63;
    const int wave = tid >> 6;
    const int wm = (wave >> 1) * 64;
    const int wn = (wave & 1) * 64;
    const int m0 = blockIdx.y * 128;
    const int n0 = blockIdx.x * 128;
    const int lm = lane & 15;
    const int kq = lane >> 4;

    f32x4 acc[4][4] = {};

    for (int k0 = 0; k0 < K; k0 += 32) {
        __syncthreads();
        #pragma unroll
        for (int r = 0; r < 2; r++) {
            int flat = r * 256 + tid;
            int row  = flat >> 2;
            int off  = (flat & 3) * 16;
            const char* ga = (const char*)(A + (size_t)(m0 + row) * K + k0) + off;
            char* la = (char*)As + flat * 16;
            __builtin_amdgcn_global_load_lds(
                (const __attribute__((address_space(1))) void*)ga,
                (__attribute__((address_space(3))) void*)la, 16, 0, 0);
            const char* gb = (const char*)(Bt + (size_t)(n0 + row) * K + k0) + off;
            char* lb = (char*)Bs + flat * 16;
            __builtin_amdgcn_global_load_lds(
                (const __attribute__((address_space(1))) void*)gb,
                (__attribute__((address_space(3))) void*)lb, 16, 0, 0);
        }
        __syncthreads();

        bf16x8 af[4], bf[4];
        #pragma unroll
        for (int t = 0; t < 4; t++) {
            af[t] = *(const bf16x8*)&As[(wm + t * 16 + lm) * 32 + kq * 8];
            bf[t] = *(const bf16x8*)&Bs[(wn + t * 16 + lm) * 32 + kq * 8];
        }
        #pragma unroll
        for (int i = 0; i < 4; i++)
            #pragma unroll
            for (int j = 0; j < 4; j++)
                acc[i][j] = __builtin_amdgcn_mfma_f32_16x16x32_bf16(
                    af[i], bf[j], acc[i][j], 0, 0, 0);
    }

    const int r0 = kq * 4;
    #pragma unroll
    for (int i = 0; i < 4; i++) {
        #pragma unroll
        for (int j = 0; j < 4; j++) {
            int col = n0 + wn + j * 16 + lm;
            float bv = bias[col];
            float sc = (col < nscale) ? QSCALE : 1.0f;
            #pragma unroll
            for (int r = 0; r < 4; r++) {
                int row = m0 + wm + i * 16 + r0 + r;
                float val = (acc[i][j][r] + bv) * sc;
                if (OUT_BF16) ((__bf16*)Cv)[(size_t)row * N + col] = (__bf16)val;
                else          ((float*)Cv)[(size_t)row * N + col] = val;
            }
        }
    }
}

// ---------------------------------------------------------------------------
// K-parallel MFMA flash attention (causal), bf16 in/out, fp32 accum.
// Block = 256 threads = 4 waves; block owns 64 q-rows. Wave w processes
// k-tiles t = w, w+4, ... INDEPENDENTLY (no barriers in the k-loop),
// accumulating private unnormalized (O, l); 3-barrier LDS combine at end.
//
// Round 4: 32x32x16 MFMA + FULLY IN-REGISTER P (T12). Natural block order
// restored (XCD = bh%8 already clusters 4 bh/XCD; the r2/r3 remap was -13%).
//
// QK^T swapped: S^T = mfma(K,Q) with the 32x32 C-layout
//   col = q = lane&31 (ALL 16 regs!), row = k = (r&3)+8*(r>>2)+4*(lane>>5).
// So each lane owns 16 score values of ONE q-row; the PV A-frag
// (lane holds P[q=lane&31][k=(lane>>5)*8+j]) differs only by the
// lane<32 / lane>=32 half-split -> 8 v_cvt_pk_bf16_f32 + 4
// v_permlane32_swap_b32 per 32x32 block produce both A-frags, no LDS.
// Row-sums l are fully lane-local (+1 shfl_xor(32) at the end).
// ---------------------------------------------------------------------------
__global__ __launch_bounds__(256) void attn_kpar_mfma(
    const __bf16* __restrict__ qkv, const __bf16* __restrict__ vt,
    __bf16* __restrict__ attn)
{
    // smem only for the end combine: Ored[2][64][66] f32 (33792 B) + lred[2][64]
    __shared__ __align__(16) char smem[34304];

    const int tid  = threadIdx.x;
    const int wave = tid >> 6;
    const int lane = tid & 63;
    const int l31  = lane & 31;
    const int hi   = lane >> 5;
    const int hi4  = hi * 4;
    const int hi8  = hi * 8;

    const int bh = blockIdx.x;                 // natural: XCD = bh & 7
    const int b  = bh >> 4;
    const int h  = bh & 15;
    const int qblk = (int)(gridDim.y - 1) - blockIdx.y;   // heavy first
    const int q0 = qblk * 64;

    const size_t base = (size_t)b * SEQ * QKV3;
    const int hoff = h * HDIM;
    const __bf16* vbase = vt + (size_t)bh * 64 * SEQ;

    // Q B-frags: aq[qh][ds] = Q[q0+qh*32+l31][ds*16 + hi*8 .. +7]
    // (pre-scaled by log2(e)/8 in the QKV GEMM epilogue)
    bf16x8 aq[2][4];
    #pragma unroll
    for (int qh = 0; qh < 2; qh++) {
        const __bf16* qrow = qkv + base +
            (size_t)(q0 + qh * 32 + l31) * QKV3 + hoff + hi8;
        #pragma unroll
        for (int ds = 0; ds < 4; ds++)
            aq[qh][ds] = *(const bf16x8*)(qrow + ds * 16);
    }

    // O accumulators: acc[qh][dh]: lane holds O[q=(r&3)+8*(r>>2)+4*hi + qh*32]
    //                                        [d = dh*32 + l31]
    f32x16 acc[2][2] = {};
    float lpart[2] = {};          // per-lane partial row-sum for q = qh*32+l31

    const int ntiles = qblk + 1;  // 64-k tiles covering [0, q0+63]

    for (int t = wave; t < ntiles; t += 4) {
        const int k0 = t * 64;
        const bool diag = (t == ntiles - 1);

        // K A-frags first (QK's waitcnt then leaves V loads in flight):
        // kf[kh][ds] = K[k0+kh*32+l31][ds*16 + hi*8 .. +7]
        bf16x8 kf[2][4];
        #pragma unroll
        for (int kh = 0; kh < 2; kh++) {
            const __bf16* krow = qkv + base +
                (size_t)(k0 + kh * 32 + l31) * QKV3 + EMBD + hoff + hi8;
            #pragma unroll
            for (int ds = 0; ds < 4; ds++)
                kf[kh][ds] = *(const bf16x8*)(krow + ds * 16);
        }
        // V B-frags: vf[kh][ks][dh] = V[k0+kh*32+ks*16+hi*8+j][dh*32+l31]
        bf16x8 vf[2][2][2];
        #pragma unroll
        for (int kh = 0; kh < 2; kh++)
            #pragma unroll
            for (int ks = 0; ks < 2; ks++)
                #pragma unroll
                for (int dh = 0; dh < 2; dh++)
                    vf[kh][ks][dh] = *(const bf16x8*)(vbase
                        + (size_t)(dh * 32 + l31) * SEQ
                        + k0 + kh * 32 + ks * 16 + hi8);

        #pragma unroll
        for (int kh = 0; kh < 2; kh++) {
            #pragma unroll
            for (int qh = 0; qh < 2; qh++) {
                // S^T block: 4 chained MFMAs over the d dimension
                f32x16 s = {};
                #pragma unroll
                for (int ds = 0; ds < 4; ds++)
                    s = __builtin_amdgcn_mfma_f32_32x32x16_bf16(
                        kf[kh][ds], aq[qh][ds], s, 0, 0, 0);

                // exp2 (+ causal mask on the diagonal tile), lane-local l-sum
                float p[16];
                const int qa = q0 + qh * 32 + l31;
                if (diag) {
                    const int kb = k0 + kh * 32 + hi4;
                    #pragma unroll
                    for (int r = 0; r < 16; r++) {
                        const int ka = kb + (r & 3) + 8 * (r >> 2);
                        float v = fast_exp2(fminf(s[r], SCLAMP));
                        p[r] = (ka > qa) ? 0.f : v;
                        lpart[qh] += p[r];
                    }
                } else {
                    #pragma unroll
                    for (int r = 0; r < 16; r++) {
                        p[r] = fast_exp2(fminf(s[r], SCLAMP));
                        lpart[qh] += p[r];
                    }
                }

                // pack to bf16 + half-swap -> PV A-frags (no LDS round trip)
                unsigned X0 = pk_bf16(p[0],  p[1]),  X1 = pk_bf16(p[2],  p[3]);
                unsigned Y0 = pk_bf16(p[4],  p[5]),  Y1 = pk_bf16(p[6],  p[7]);
                unsigned Z0 = pk_bf16(p[8],  p[9]),  Z1 = pk_bf16(p[10], p[11]);
                unsigned W0 = pk_bf16(p[12], p[13]), W1 = pk_bf16(p[14], p[15]);
                pl32_swap(X0, Y0); pl32_swap(X1, Y1);
                pl32_swap(Z0, W0); pl32_swap(Z1, W1);
                bf16x8 pa0 = frag4(X0, X1, Y0, Y1);   // k 0..15  of this kh
                bf16x8 pa1 = frag4(Z0, Z1, W0, W1);   // k 16..31 of this kh

                // O += P V
                __builtin_amdgcn_s_setprio(1);
                #pragma unroll
                for (int dh = 0; dh < 2; dh++) {
                    acc[qh][dh] = __builtin_amdgcn_mfma_f32_32x32x16_bf16(
                        pa0, vf[kh][0][dh], acc[qh][dh], 0, 0, 0);
                    acc[qh][dh] = __builtin_amdgcn_mfma_f32_32x32x16_bf16(
                        pa1, vf[kh][1][dh], acc[qh][dh], 0, 0, 0);
                }
                __builtin_amdgcn_s_setprio(0);
            }
        }
    }

    // Complete row-sums: partner lane (xor 32) holds the complementary k-halves
    #pragma unroll
    for (int qh = 0; qh < 2; qh++) {
        float v = lpart[qh];
        v += __shfl_xor(v, 32);
        lpart[qh] = v;
    }

    float* Ored = (float*)smem;                    // [2][64][66]
    float* lred = (float*)(smem + 33792);          // [2][64]

    if (wave < 2) {
        float* R = Ored + wave * (64 * 66);
        #pragma unroll
        for (int qh = 0; qh < 2; qh++) {
            #pragma unroll
            for (int dh = 0; dh < 2; dh++)
                #pragma unroll
                for (int r = 0; r < 16; r++)
                    R[(qh * 32 + (r & 3) + 8 * (r >> 2) + hi4) * 66
                      + dh * 32 + l31] = acc[qh][dh][r];
            if (hi == 0) lred[wave * 64 + qh * 32 + l31] = lpart[qh];
        }
    }
    __syncthreads();
    if (wave >= 2) {
        float* R = Ored + (wave - 2) * (64 * 66);
        #pragma unroll
        for (int qh = 0; qh < 2; qh++) {
            #pragma unroll
            for (int dh = 0; dh < 2; dh++)
                #pragma unroll
                for (int r = 0; r < 16; r++)
                    R[(qh * 32 + (r & 3) + 8 * (r >> 2) + hi4) * 66
                      + dh * 32 + l31] += acc[qh][dh][r];
            if (hi == 0) lred[(wave - 2) * 64 + qh * 32 + l31] += lpart[qh];
        }
    }
    __syncthreads();

    // Final: each thread does one 8-col chunk of one row; 2 iterations, 64 rows
    #pragma unroll
    for (int it = 0; it < 2; it++) {
        const int flat = it * 256 + tid;
        const int row = flat >> 3;         // 0..63
        const int cg  = flat & 7;          // 8-col group
        const float l = lred[row] + lred[64 + row];
        const float inv = 1.f / l;
        const float* R0 = Ored + row * 66 + cg * 8;
        const float* R1 = R0 + 64 * 66;
        bf16x8 o;
        #pragma unroll
        for (int i = 0; i < 8; i++) o[i] = (__bf16)((R0[i] + R1[i]) * inv);
        *(bf16x8*)&attn[((size_t)b * SEQ + q0 + row) * EMBD + hoff + cg * 8] = o;
    }
}

// ---------------------------------------------------------------------------
extern "C" void kernel_launch(void* const* d_in, const int* in_sizes, int n_in,
                              void* d_out, int out_size, void* d_ws, size_t ws_size,
                              hipStream_t stream)
{
    const float* x     = (const float*)d_in[0];  // [2,2048,1024]
    const float* W_qkv = (const float*)d_in[1];  // [1024,3072]
    const float* b_qkv = (const float*)d_in[2];  // [3072]
    const float* W_out = (const float*)d_in[3];  // [1024,1024]
    const float* b_out = (const float*)d_in[4];  // [1024]
    float* out = (float*)d_out;                  // [2,2048,1024] fp32

    const int M = BATCH * SEQ;   // 4096

    __bf16* xbf    = (__bf16*)d_ws;                          // [4096,1024]  8 MB
    __bf16* Wqkv_t = xbf    + (size_t)M * EMBD;              // [3072,1024]  6 MB
    __bf16* Wout_t = Wqkv_t + (size_t)QKV3 * EMBD;           // [1024,1024]  2 MB
    __bf16* qkv    = Wout_t + (size_t)EMBD * EMBD;           // [4096,3072] 24 MB
    __bf16* attn   = qkv    + (size_t)M * QKV3;              // [4096,1024]  8 MB
    __bf16* vtbuf  = attn   + (size_t)M * EMBD;              // [32,64,2048]  8 MB

    // 0) Casts
    cast_f32_bf16<<<(M * EMBD) / (256 * 8), 256, 0, stream>>>(x, xbf);
    {
        dim3 g(QKV3 / 64, EMBD / 64);
        transpose_cast_bf16<<<g, 256, 0, stream>>>(W_qkv, Wqkv_t, EMBD, QKV3);
    }
    {
        dim3 g(EMBD / 64, EMBD / 64);
        transpose_cast_bf16<<<g, 256, 0, stream>>>(W_out, Wout_t, EMBD, EMBD);
    }
    // 1) QKV projection (bf16 out; Q columns pre-scaled by log2(e)/8)
    {
        dim3 grid(QKV3 / 128, M / 128);
        gemm_bt_mfma<true><<<grid, 256, 0, stream>>>(xbf, Wqkv_t, b_qkv, qkv, M, QKV3, EMBD, EMBD);
    }
    // 1b) Pre-transpose V to [bh][d][k]
    {
        dim3 grid(SEQ / 64, BATCH * NHEAD);
        transpose_v_bf16<<<grid, 256, 0, stream>>>(qkv, vtbuf);
    }
    // 2) K-parallel MFMA flash causal attention (64 q/block, 32x32 MFMA,
    //    in-register P via cvt_pk + permlane32_swap)
    {
        dim3 grid(BATCH * NHEAD, SEQ / 64);
        attn_kpar_mfma<<<grid, 256, 0, stream>>>(qkv, vtbuf, attn);
    }
    // 3) Output projection (fp32 out)
    {
        dim3 grid(EMBD / 128, M / 128);
        gemm_bt_mfma<false><<<grid, 256, 0, stream>>>(attn, Wout_t, b_out, out, M, EMBD, EMBD, 0);
    }
}

// Round 5
// 204.053 us; speedup vs baseline: 1.1429x; 1.0005x over previous
//
#include <hip/hip_runtime.h>
#include <hip/hip_bf16.h>

// Problem constants
#define BATCH 2
#define SEQ   2048
#define EMBD  1024
#define NHEAD 16
#define HDIM  64
#define QKV3  (3 * EMBD)   // 3072

// Q pre-scale folded into the QKV GEMM epilogue: (1/sqrt(HDIM)) * log2(e)
// so attention can use hardware exp2 directly (v_exp_f32 is 2^x).
#define QSCALE 0.18033688011112042f
// clamp for exp2 argument = 60 * log2(e)  (same guard as old exp clamp 60)
#define SCLAMP 86.56f

typedef __attribute__((ext_vector_type(8)))  __bf16 bf16x8;
typedef __attribute__((ext_vector_type(4)))  __bf16 bf16x4;
typedef __attribute__((ext_vector_type(4)))  float  f32x4;
typedef __attribute__((ext_vector_type(16))) float  f32x16;
typedef __attribute__((ext_vector_type(4)))  unsigned int u32x4;

__device__ __forceinline__ float fast_exp2(float x) {
#if __has_builtin(__builtin_amdgcn_exp2f)
    return __builtin_amdgcn_exp2f(x);
#else
    return exp2f(x);
#endif
}

// pack two f32 -> one dword of 2 bf16 (lo = a, hi = b); no builtin on gfx950
__device__ __forceinline__ unsigned pk_bf16(float a, float b) {
    unsigned d;
    asm("v_cvt_pk_bf16_f32 %0, %1, %2" : "=v"(d) : "v"(a), "v"(b));
    return d;
}

// v_permlane32_swap_b32: new a[32:63] = old b[0:31], new b[0:31] = old a[32:63]
__device__ __forceinline__ void pl32_swap(unsigned &a, unsigned &b) {
    asm volatile("v_permlane32_swap_b32 %0, %1" : "+v"(a), "+v"(b));
}

__device__ __forceinline__ bf16x8 frag4(unsigned a, unsigned b, unsigned c, unsigned d) {
    u32x4 u = {a, b, c, d};
    return __builtin_bit_cast(bf16x8, u);
}

// ---------------------------------------------------------------------------
// fp32 -> bf16 elementwise cast (8 elems/thread)
// ---------------------------------------------------------------------------
__global__ __launch_bounds__(256) void cast_f32_bf16(
    const float* __restrict__ in, __bf16* __restrict__ out)
{
    int i = (blockIdx.x * 256 + threadIdx.x) * 8;
    float4 a = *(const float4*)&in[i];
    float4 b = *(const float4*)&in[i + 4];
    bf16x8 o;
    o[0] = (__bf16)a.x; o[1] = (__bf16)a.y; o[2] = (__bf16)a.z; o[3] = (__bf16)a.w;
    o[4] = (__bf16)b.x; o[5] = (__bf16)b.y; o[6] = (__bf16)b.z; o[7] = (__bf16)b.w;
    *(bf16x8*)&out[i] = o;
}

// ---------------------------------------------------------------------------
// fp32 [K,N] -> bf16 [N,K] transpose+cast, 64x64 LDS tile, 256 threads
// ---------------------------------------------------------------------------
__global__ __launch_bounds__(256) void transpose_cast_bf16(
    const float* __restrict__ in, __bf16* __restrict__ out, int K, int N)
{
    __shared__ float t[64][65];
    const int k0 = blockIdx.y * 64, n0 = blockIdx.x * 64;
    const int tid = threadIdx.x;
    #pragma unroll
    for (int p = 0; p < 4; p++) {
        int kr = p * 16 + (tid >> 4);
        int c4 = (tid & 15) * 4;
        float4 v = *(const float4*)&in[(size_t)(k0 + kr) * N + n0 + c4];
        t[kr][c4] = v.x; t[kr][c4 + 1] = v.y; t[kr][c4 + 2] = v.z; t[kr][c4 + 3] = v.w;
    }
    __syncthreads();
    #pragma unroll
    for (int p = 0; p < 4; p++) {
        int nr = p * 16 + (tid >> 4);
        int k4 = (tid & 15) * 4;
        bf16x4 o;
        o[0] = (__bf16)t[k4 + 0][nr];
        o[1] = (__bf16)t[k4 + 1][nr];
        o[2] = (__bf16)t[k4 + 2][nr];
        o[3] = (__bf16)t[k4 + 3][nr];
        *(bf16x4*)&out[(size_t)(n0 + nr) * K + k0 + k4] = o;
    }
}

// ---------------------------------------------------------------------------
// bf16 V-transpose: qkv V region [k][d] per (b,h) -> vt[bh][d][k]
// ---------------------------------------------------------------------------
__global__ __launch_bounds__(256) void transpose_v_bf16(
    const __bf16* __restrict__ qkv, __bf16* __restrict__ vt)
{
    __shared__ __bf16 t[64][72];
    const int k0 = blockIdx.x * 64;
    const int bh = blockIdx.y;
    const int b = bh >> 4, h = bh & 15;
    const size_t base = (size_t)b * SEQ * QKV3 + 2 * EMBD + h * HDIM;
    const int tid = threadIdx.x;
    #pragma unroll
    for (int it = 0; it < 2; it++) {
        int flat = it * 256 + tid;      // 0..511
        int kr = flat >> 3;             // 0..63
        int d0 = (flat & 7) * 8;
        bf16x8 v = *(const bf16x8*)&qkv[base + (size_t)(k0 + kr) * QKV3 + d0];
        #pragma unroll
        for (int i = 0; i < 8; i++) t[kr][d0 + i] = v[i];
    }
    __syncthreads();
    #pragma unroll
    for (int it = 0; it < 2; it++) {
        int flat = it * 256 + tid;
        int d  = flat >> 3;             // 0..63
        int kc = (flat & 7) * 8;
        bf16x8 o;
        #pragma unroll
        for (int i = 0; i < 8; i++) o[i] = t[kc + i][d];
        *(bf16x8*)&vt[((size_t)bh * 64 + d) * SEQ + k0 + kc] = o;
    }
}

// ---------------------------------------------------------------------------
// bf16 MFMA GEMM (B^T form): C[M,N] = A[M,K] @ Bt[N,K]^T + bias[N]
// 128x128 block tile, 4 waves (2x2), mfma_f32_16x16x32_bf16, BK=32,
// global_load_lds width-16 staging. Columns < nscale get *QSCALE (folds the
// attention 1/sqrt(d) AND log2(e) into the Q region of the QKV projection).
// ---------------------------------------------------------------------------
template<bool OUT_BF16>
__global__ __launch_bounds__(256) void gemm_bt_mfma(
    const __bf16* __restrict__ A,   // [M,K]
    const __bf16* __restrict__ Bt,  // [N,K]
    const float* __restrict__ bias, // [N]
    void* __restrict__ Cv,          // [M,N]
    int M, int N, int K, int nscale)
{
    __shared__ __align__(16) __bf16 As[128 * 32];
    __shared__ __align__(16) __bf16 Bs[128 * 32];

    const int tid  = threadIdx.x;
    const int lane = tid & 63;
    const int wave = tid >> 6;
    const int wm = (wave >> 1) * 64;
    const int wn = (wave & 1) * 64;
    const int m0 = blockIdx.y * 128;
    const int n0 = blockIdx.x * 128;
    const int lm = lane & 15;
    const int kq = lane >> 4;

    f32x4 acc[4][4] = {};

    for (int k0 = 0; k0 < K; k0 += 32) {
        __syncthreads();
        #pragma unroll
        for (int r = 0; r < 2; r++) {
            int flat = r * 256 + tid;
            int row  = flat >> 2;
            int off  = (flat & 3) * 16;
            const char* ga = (const char*)(A + (size_t)(m0 + row) * K + k0) + off;
            char* la = (char*)As + flat * 16;
            __builtin_amdgcn_global_load_lds(
                (const __attribute__((address_space(1))) void*)ga,
                (__attribute__((address_space(3))) void*)la, 16, 0, 0);
            const char* gb = (const char*)(Bt + (size_t)(n0 + row) * K + k0) + off;
            char* lb = (char*)Bs + flat * 16;
            __builtin_amdgcn_global_load_lds(
                (const __attribute__((address_space(1))) void*)gb,
                (__attribute__((address_space(3))) void*)lb, 16, 0, 0);
        }
        __syncthreads();

        bf16x8 af[4], bf[4];
        #pragma unroll
        for (int t = 0; t < 4; t++) {
            af[t] = *(const bf16x8*)&As[(wm + t * 16 + lm) * 32 + kq * 8];
            bf[t] = *(const bf16x8*)&Bs[(wn + t * 16 + lm) * 32 + kq * 8];
        }
        #pragma unroll
        for (int i = 0; i < 4; i++)
            #pragma unroll
            for (int j = 0; j < 4; j++)
                acc[i][j] = __builtin_amdgcn_mfma_f32_16x16x32_bf16(
                    af[i], bf[j], acc[i][j], 0, 0, 0);
    }

    const int r0 = kq * 4;
    #pragma unroll
    for (int i = 0; i < 4; i++) {
        #pragma unroll
        for (int j = 0; j < 4; j++) {
            int col = n0 + wn + j * 16 + lm;
            float bv = bias[col];
            float sc = (col < nscale) ? QSCALE : 1.0f;
            #pragma unroll
            for (int r = 0; r < 4; r++) {
                int row = m0 + wm + i * 16 + r0 + r;
                float val = (acc[i][j][r] + bv) * sc;
                if (OUT_BF16) ((__bf16*)Cv)[(size_t)row * N + col] = (__bf16)val;
                else          ((float*)Cv)[(size_t)row * N + col] = val;
            }
        }
    }
}

// ---------------------------------------------------------------------------
// K-parallel MFMA flash attention (causal), bf16 in/out, fp32 accum.
// Block = 256 threads = 4 waves. Round 5: TRIANGULAR PAIRING — each block
// owns TWO 64-row q-tiles, qblk = 31-pi (heavy) then pi (light), processed
// as two sequential phases. Every block does exactly 33 k-tiles, and the
// grid is 512 blocks = exactly 2 blocks/CU, all resident simultaneously:
// no dispatch rounds, no causal work-imbalance tail (the r4 bottleneck:
// 9.8% time-avg occupancy vs 8 waves/CU capacity).
//
// Per phase, wave w processes k-tiles t = w, w+4, ... INDEPENDENTLY (no
// barriers in the k-loop) accumulating private unnormalized (O, l);
// 3-barrier LDS tree combine per phase.
//
// 32x32x16 MFMA, fully in-register P (T12): QK^T swapped (S^T = mfma(K,Q)),
// C-layout col = q = lane&31 for all 16 regs -> P rows lane-local; PV A-frag
// needs only the lane<32/lane>=32 half-swap: 8 v_cvt_pk_bf16_f32 + 4
// v_permlane32_swap_b32 per 32x32 block. Row-sums l lane-local via 4
// independent sub-accumulators (breaks the 32-deep serial add chain),
// folded + one shfl_xor(32) at end of phase.
// ---------------------------------------------------------------------------
__global__ __launch_bounds__(256) void attn_kpar_mfma(
    const __bf16* __restrict__ qkv, const __bf16* __restrict__ vt,
    __bf16* __restrict__ attn)
{
    // smem only for the combine: Ored[2][64][66] f32 (33792 B) + lred[2][64]
    __shared__ __align__(16) char smem[34304];

    const int tid  = threadIdx.x;
    const int wave = tid >> 6;
    const int lane = tid & 63;
    const int l31  = lane & 31;
    const int hi   = lane >> 5;
    const int hi4  = hi * 4;
    const int hi8  = hi * 8;

    const int bh = blockIdx.x;                 // natural: XCD = bh & 7 -> 4 bh/XCD
    const int b  = bh >> 4;
    const int h  = bh & 15;
    const int pi = blockIdx.y;                 // 0..15 pair index

    const size_t base = (size_t)b * SEQ * QKV3;
    const int hoff = h * HDIM;
    const __bf16* vbase = vt + (size_t)bh * 64 * SEQ;

    float* Ored = (float*)smem;                    // [2][64][66]
    float* lred = (float*)(smem + 33792);          // [2][64]

    #pragma unroll 1
    for (int ph = 0; ph < 2; ph++) {
        const int qblk = ph ? pi : (31 - pi);  // heavy tile first, then light
        const int q0 = qblk * 64;

        // Q B-frags: aq[qh][ds] = Q[q0+qh*32+l31][ds*16 + hi*8 .. +7]
        // (pre-scaled by log2(e)/8 in the QKV GEMM epilogue)
        bf16x8 aq[2][4];
        #pragma unroll
        for (int qh = 0; qh < 2; qh++) {
            const __bf16* qrow = qkv + base +
                (size_t)(q0 + qh * 32 + l31) * QKV3 + hoff + hi8;
            #pragma unroll
            for (int ds = 0; ds < 4; ds++)
                aq[qh][ds] = *(const bf16x8*)(qrow + ds * 16);
        }

        // O accumulators: acc[qh][dh]: lane holds
        //   O[q = (r&3)+8*(r>>2)+4*hi + qh*32][d = dh*32 + l31]
        f32x16 acc[2][2] = {};
        float lsub[2][4] = {};    // 4 independent row-sum chains per qh

        const int ntiles = qblk + 1;  // 64-k tiles covering [0, q0+63]

        for (int t = wave; t < ntiles; t += 4) {
            const int k0 = t * 64;
            const bool diag = (t == ntiles - 1);

            // K A-frags first (QK's waitcnt then leaves V loads in flight)
            bf16x8 kf[2][4];
            #pragma unroll
            for (int kh = 0; kh < 2; kh++) {
                const __bf16* krow = qkv + base +
                    (size_t)(k0 + kh * 32 + l31) * QKV3 + EMBD + hoff + hi8;
                #pragma unroll
                for (int ds = 0; ds < 4; ds++)
                    kf[kh][ds] = *(const bf16x8*)(krow + ds * 16);
            }
            // V B-frags: vf[kh][ks][dh] = V[k0+kh*32+ks*16+hi*8+j][dh*32+l31]
            bf16x8 vf[2][2][2];
            #pragma unroll
            for (int kh = 0; kh < 2; kh++)
                #pragma unroll
                for (int ks = 0; ks < 2; ks++)
                    #pragma unroll
                    for (int dh = 0; dh < 2; dh++)
                        vf[kh][ks][dh] = *(const bf16x8*)(vbase
                            + (size_t)(dh * 32 + l31) * SEQ
                            + k0 + kh * 32 + ks * 16 + hi8);

            #pragma unroll
            for (int kh = 0; kh < 2; kh++) {
                #pragma unroll
                for (int qh = 0; qh < 2; qh++) {
                    // S^T block: 4 chained MFMAs over the d dimension
                    f32x16 s = {};
                    #pragma unroll
                    for (int ds = 0; ds < 4; ds++)
                        s = __builtin_amdgcn_mfma_f32_32x32x16_bf16(
                            kf[kh][ds], aq[qh][ds], s, 0, 0, 0);

                    // exp2 (+ causal mask on diag tile), 4-way split l-sum
                    float p[16];
                    const int qa = q0 + qh * 32 + l31;
                    if (diag) {
                        const int kb = k0 + kh * 32 + hi4;
                        #pragma unroll
                        for (int r = 0; r < 16; r++) {
                            const int ka = kb + (r & 3) + 8 * (r >> 2);
                            float v = fast_exp2(fminf(s[r], SCLAMP));
                            p[r] = (ka > qa) ? 0.f : v;
                            lsub[qh][r & 3] += p[r];
                        }
                    } else {
                        #pragma unroll
                        for (int r = 0; r < 16; r++) {
                            p[r] = fast_exp2(fminf(s[r], SCLAMP));
                            lsub[qh][r & 3] += p[r];
                        }
                    }

                    // pack to bf16 + half-swap -> PV A-frags (no LDS)
                    unsigned X0 = pk_bf16(p[0],  p[1]),  X1 = pk_bf16(p[2],  p[3]);
                    unsigned Y0 = pk_bf16(p[4],  p[5]),  Y1 = pk_bf16(p[6],  p[7]);
                    unsigned Z0 = pk_bf16(p[8],  p[9]),  Z1 = pk_bf16(p[10], p[11]);
                    unsigned W0 = pk_bf16(p[12], p[13]), W1 = pk_bf16(p[14], p[15]);
                    pl32_swap(X0, Y0); pl32_swap(X1, Y1);
                    pl32_swap(Z0, W0); pl32_swap(Z1, W1);
                    bf16x8 pa0 = frag4(X0, X1, Y0, Y1);   // k 0..15  of this kh
                    bf16x8 pa1 = frag4(Z0, Z1, W0, W1);   // k 16..31 of this kh

                    // O += P V
                    __builtin_amdgcn_s_setprio(1);
                    #pragma unroll
                    for (int dh = 0; dh < 2; dh++) {
                        acc[qh][dh] = __builtin_amdgcn_mfma_f32_32x32x16_bf16(
                            pa0, vf[kh][0][dh], acc[qh][dh], 0, 0, 0);
                        acc[qh][dh] = __builtin_amdgcn_mfma_f32_32x32x16_bf16(
                            pa1, vf[kh][1][dh], acc[qh][dh], 0, 0, 0);
                    }
                    __builtin_amdgcn_s_setprio(0);
                }
            }
        }

        // Fold sub-chains; partner lane (xor 32) holds complementary k-halves
        float lpart[2];
        #pragma unroll
        for (int qh = 0; qh < 2; qh++) {
            float v = (lsub[qh][0] + lsub[qh][1]) + (lsub[qh][2] + lsub[qh][3]);
            v += __shfl_xor(v, 32);
            lpart[qh] = v;
        }

        // Barrier: in phase 1 this also protects smem against the previous
        // phase's normalize reads (k-loop itself never touches smem).
        __syncthreads();

        if (wave < 2) {
            float* R = Ored + wave * (64 * 66);
            #pragma unroll
            for (int qh = 0; qh < 2; qh++) {
                #pragma unroll
                for (int dh = 0; dh < 2; dh++)
                    #pragma unroll
                    for (int r = 0; r < 16; r++)
                        R[(qh * 32 + (r & 3) + 8 * (r >> 2) + hi4) * 66
                          + dh * 32 + l31] = acc[qh][dh][r];
                if (hi == 0) lred[wave * 64 + qh * 32 + l31] = lpart[qh];
            }
        }
        __syncthreads();
        if (wave >= 2) {
            float* R = Ored + (wave - 2) * (64 * 66);
            #pragma unroll
            for (int qh = 0; qh < 2; qh++) {
                #pragma unroll
                for (int dh = 0; dh < 2; dh++)
                    #pragma unroll
                    for (int r = 0; r < 16; r++)
                        R[(qh * 32 + (r & 3) + 8 * (r >> 2) + hi4) * 66
                          + dh * 32 + l31] += acc[qh][dh][r];
                if (hi == 0) lred[(wave - 2) * 64 + qh * 32 + l31] += lpart[qh];
            }
        }
        __syncthreads();

        // Final: each thread one 8-col chunk of one row; 2 iterations, 64 rows
        #pragma unroll
        for (int it = 0; it < 2; it++) {
            const int flat = it * 256 + tid;
            const int row = flat >> 3;         // 0..63
            const int cg  = flat & 7;          // 8-col group
            const float l = lred[row] + lred[64 + row];
            const float inv = 1.f / l;
            const float* R0 = Ored + row * 66 + cg * 8;
            const float* R1 = R0 + 64 * 66;
            bf16x8 o;
            #pragma unroll
            for (int i = 0; i < 8; i++) o[i] = (__bf16)((R0[i] + R1[i]) * inv);
            *(bf16x8*)&attn[((size_t)b * SEQ + q0 + row) * EMBD + hoff + cg * 8] = o;
        }
    }
}

// ---------------------------------------------------------------------------
extern "C" void kernel_launch(void* const* d_in, const int* in_sizes, int n_in,
                              void* d_out, int out_size, void* d_ws, size_t ws_size,
                              hipStream_t stream)
{
    const float* x     = (const float*)d_in[0];  // [2,2048,1024]
    const float* W_qkv = (const float*)d_in[1];  // [1024,3072]
    const float* b_qkv = (const float*)d_in[2];  // [3072]
    const float* W_out = (const float*)d_in[3];  // [1024,1024]
    const float* b_out = (const float*)d_in[4];  // [1024]
    float* out = (float*)d_out;                  // [2,2048,1024] fp32

    const int M = BATCH * SEQ;   // 4096

    __bf16* xbf    = (__bf16*)d_ws;                          // [4096,1024]  8 MB
    __bf16* Wqkv_t = xbf    + (size_t)M * EMBD;              // [3072,1024]  6 MB
    __bf16* Wout_t = Wqkv_t + (size_t)QKV3 * EMBD;           // [1024,1024]  2 MB
    __bf16* qkv    = Wout_t + (size_t)EMBD * EMBD;           // [4096,3072] 24 MB
    __bf16* attn   = qkv    + (size_t)M * QKV3;              // [4096,1024]  8 MB
    __bf16* vtbuf  = attn   + (size_t)M * EMBD;              // [32,64,2048]  8 MB

    // 0) Casts
    cast_f32_bf16<<<(M * EMBD) / (256 * 8), 256, 0, stream>>>(x, xbf);
    {
        dim3 g(QKV3 / 64, EMBD / 64);
        transpose_cast_bf16<<<g, 256, 0, stream>>>(W_qkv, Wqkv_t, EMBD, QKV3);
    }
    {
        dim3 g(EMBD / 64, EMBD / 64);
        transpose_cast_bf16<<<g, 256, 0, stream>>>(W_out, Wout_t, EMBD, EMBD);
    }
    // 1) QKV projection (bf16 out; Q columns pre-scaled by log2(e)/8)
    {
        dim3 grid(QKV3 / 128, M / 128);
        gemm_bt_mfma<true><<<grid, 256, 0, stream>>>(xbf, Wqkv_t, b_qkv, qkv, M, QKV3, EMBD, EMBD);
    }
    // 1b) Pre-transpose V to [bh][d][k]
    {
        dim3 grid(SEQ / 64, BATCH * NHEAD);
        transpose_v_bf16<<<grid, 256, 0, stream>>>(qkv, vtbuf);
    }
    // 2) K-parallel MFMA flash causal attention: triangular-paired blocks,
    //    512 blocks = exactly 2 blocks/CU, uniform 33 k-tiles per block
    {
        dim3 grid(BATCH * NHEAD, SEQ / 128);
        attn_kpar_mfma<<<grid, 256, 0, stream>>>(qkv, vtbuf, attn);
    }
    // 3) Output projection (fp32 out)
    {
        dim3 grid(EMBD / 128, M / 128);
        gemm_bt_mfma<false><<<grid, 256, 0, stream>>>(attn, Wout_t, b_out, out, M, EMBD, EMBD, 0);
    }
}

// Round 6
// 197.716 us; speedup vs baseline: 1.1796x; 1.0320x over previous
//
#include <hip/hip_runtime.h>
#include <hip/hip_bf16.h>

// Problem constants
#define BATCH 2
#define SEQ   2048
#define EMBD  1024
#define NHEAD 16
#define HDIM  64
#define QKV3  (3 * EMBD)   // 3072

// Q pre-scale folded into the QKV GEMM epilogue: (1/sqrt(HDIM)) * log2(e)
// so attention can use hardware exp2 directly (v_exp_f32 is 2^x).
#define QSCALE 0.18033688011112042f
// clamp for exp2 argument = 60 * log2(e)  (same guard as old exp clamp 60)
#define SCLAMP 86.56f

typedef __attribute__((ext_vector_type(8))) __bf16 bf16x8;
typedef __attribute__((ext_vector_type(4))) __bf16 bf16x4;
typedef __attribute__((ext_vector_type(4))) float f32x4;

__device__ __forceinline__ float fast_exp2(float x) {
#if __has_builtin(__builtin_amdgcn_exp2f)
    return __builtin_amdgcn_exp2f(x);
#else
    return exp2f(x);
#endif
}

// ---------------------------------------------------------------------------
// fp32 -> bf16 elementwise cast (8 elems/thread)
// ---------------------------------------------------------------------------
__global__ __launch_bounds__(256) void cast_f32_bf16(
    const float* __restrict__ in, __bf16* __restrict__ out)
{
    int i = (blockIdx.x * 256 + threadIdx.x) * 8;
    float4 a = *(const float4*)&in[i];
    float4 b = *(const float4*)&in[i + 4];
    bf16x8 o;
    o[0] = (__bf16)a.x; o[1] = (__bf16)a.y; o[2] = (__bf16)a.z; o[3] = (__bf16)a.w;
    o[4] = (__bf16)b.x; o[5] = (__bf16)b.y; o[6] = (__bf16)b.z; o[7] = (__bf16)b.w;
    *(bf16x8*)&out[i] = o;
}

// ---------------------------------------------------------------------------
// fp32 [K,N] -> bf16 [N,K] transpose+cast, 64x64 LDS tile, 256 threads
// ---------------------------------------------------------------------------
__global__ __launch_bounds__(256) void transpose_cast_bf16(
    const float* __restrict__ in, __bf16* __restrict__ out, int K, int N)
{
    __shared__ float t[64][65];
    const int k0 = blockIdx.y * 64, n0 = blockIdx.x * 64;
    const int tid = threadIdx.x;
    #pragma unroll
    for (int p = 0; p < 4; p++) {
        int kr = p * 16 + (tid >> 4);
        int c4 = (tid & 15) * 4;
        float4 v = *(const float4*)&in[(size_t)(k0 + kr) * N + n0 + c4];
        t[kr][c4] = v.x; t[kr][c4 + 1] = v.y; t[kr][c4 + 2] = v.z; t[kr][c4 + 3] = v.w;
    }
    __syncthreads();
    #pragma unroll
    for (int p = 0; p < 4; p++) {
        int nr = p * 16 + (tid >> 4);
        int k4 = (tid & 15) * 4;
        bf16x4 o;
        o[0] = (__bf16)t[k4 + 0][nr];
        o[1] = (__bf16)t[k4 + 1][nr];
        o[2] = (__bf16)t[k4 + 2][nr];
        o[3] = (__bf16)t[k4 + 3][nr];
        *(bf16x4*)&out[(size_t)(n0 + nr) * K + k0 + k4] = o;
    }
}

// ---------------------------------------------------------------------------
// bf16 V-transpose: qkv V region [k][d] per (b,h) -> vt[bh][d][k]
// ---------------------------------------------------------------------------
__global__ __launch_bounds__(256) void transpose_v_bf16(
    const __bf16* __restrict__ qkv, __bf16* __restrict__ vt)
{
    __shared__ __bf16 t[64][72];
    const int k0 = blockIdx.x * 64;
    const int bh = blockIdx.y;
    const int b = bh >> 4, h = bh & 15;
    const size_t base = (size_t)b * SEQ * QKV3 + 2 * EMBD + h * HDIM;
    const int tid = threadIdx.x;
    #pragma unroll
    for (int it = 0; it < 2; it++) {
        int flat = it * 256 + tid;      // 0..511
        int kr = flat >> 3;             // 0..63
        int d0 = (flat & 7) * 8;
        bf16x8 v = *(const bf16x8*)&qkv[base + (size_t)(k0 + kr) * QKV3 + d0];
        #pragma unroll
        for (int i = 0; i < 8; i++) t[kr][d0 + i] = v[i];
    }
    __syncthreads();
    #pragma unroll
    for (int it = 0; it < 2; it++) {
        int flat = it * 256 + tid;
        int d  = flat >> 3;             // 0..63
        int kc = (flat & 7) * 8;
        bf16x8 o;
        #pragma unroll
        for (int i = 0; i < 8; i++) o[i] = t[kc + i][d];
        *(bf16x8*)&vt[((size_t)bh * 64 + d) * SEQ + k0 + kc] = o;
    }
}

// ---------------------------------------------------------------------------
// bf16 MFMA GEMM (B^T form): C[M,N] = A[M,K] @ Bt[N,K]^T + bias[N]
// 128x128 block tile, 4 waves (2x2), mfma_f32_16x16x32_bf16, BK=32,
// global_load_lds width-16 staging. Columns < nscale get *QSCALE (folds the
// attention 1/sqrt(d) AND log2(e) into the Q region of the QKV projection).
// ---------------------------------------------------------------------------
template<bool OUT_BF16>
__global__ __launch_bounds__(256) void gemm_bt_mfma(
    const __bf16* __restrict__ A,   // [M,K]
    const __bf16* __restrict__ Bt,  // [N,K]
    const float* __restrict__ bias, // [N]
    void* __restrict__ Cv,          // [M,N]
    int M, int N, int K, int nscale)
{
    __shared__ __align__(16) __bf16 As[128 * 32];
    __shared__ __align__(16) __bf16 Bs[128 * 32];

    const int tid  = threadIdx.x;
    const int lane = tid & 63;
    const int wave = tid >> 6;
    const int wm = (wave >> 1) * 64;
    const int wn = (wave & 1) * 64;
    const int m0 = blockIdx.y * 128;
    const int n0 = blockIdx.x * 128;
    const int lm = lane & 15;
    const int kq = lane >> 4;

    f32x4 acc[4][4] = {};

    for (int k0 = 0; k0 < K; k0 += 32) {
        __syncthreads();
        #pragma unroll
        for (int r = 0; r < 2; r++) {
            int flat = r * 256 + tid;
            int row  = flat >> 2;
            int off  = (flat & 3) * 16;
            const char* ga = (const char*)(A + (size_t)(m0 + row) * K + k0) + off;
            char* la = (char*)As + flat * 16;
            __builtin_amdgcn_global_load_lds(
                (const __attribute__((address_space(1))) void*)ga,
                (__attribute__((address_space(3))) void*)la, 16, 0, 0);
            const char* gb = (const char*)(Bt + (size_t)(n0 + row) * K + k0) + off;
            char* lb = (char*)Bs + flat * 16;
            __builtin_amdgcn_global_load_lds(
                (const __attribute__((address_space(1))) void*)gb,
                (__attribute__((address_space(3))) void*)lb, 16, 0, 0);
        }
        __syncthreads();

        bf16x8 af[4], bf[4];
        #pragma unroll
        for (int t = 0; t < 4; t++) {
            af[t] = *(const bf16x8*)&As[(wm + t * 16 + lm) * 32 + kq * 8];
            bf[t] = *(const bf16x8*)&Bs[(wn + t * 16 + lm) * 32 + kq * 8];
        }
        #pragma unroll
        for (int i = 0; i < 4; i++)
            #pragma unroll
            for (int j = 0; j < 4; j++)
                acc[i][j] = __builtin_amdgcn_mfma_f32_16x16x32_bf16(
                    af[i], bf[j], acc[i][j], 0, 0, 0);
    }

    const int r0 = kq * 4;
    #pragma unroll
    for (int i = 0; i < 4; i++) {
        #pragma unroll
        for (int j = 0; j < 4; j++) {
            int col = n0 + wn + j * 16 + lm;
            float bv = bias[col];
            float sc = (col < nscale) ? QSCALE : 1.0f;
            #pragma unroll
            for (int r = 0; r < 4; r++) {
                int row = m0 + wm + i * 16 + r0 + r;
                float val = (acc[i][j][r] + bv) * sc;
                if (OUT_BF16) ((__bf16*)Cv)[(size_t)row * N + col] = (__bf16)val;
                else          ((float*)Cv)[(size_t)row * N + col] = val;
            }
        }
    }
}

// ---------------------------------------------------------------------------
// Small-tile bf16 MFMA GEMM for the output projection: C = A @ Bt^T + bias,
// fp32 out. 64x64 block tile, 4 waves (2x2, 32x32 each), BK=32.
// Rationale: the 128x128 kernel at N=1024 gives only 256 blocks = 1 block/CU
// = 1 wave/SIMD — nothing resident to hide latency. 64x64 -> 1024 blocks =
// 4 blocks/CU = 16 waves/CU (VGPR ~90, 4-waves/SIMD tier).
// ---------------------------------------------------------------------------
__global__ __launch_bounds__(256) void gemm_bt_mfma64(
    const __bf16* __restrict__ A,   // [M,K]
    const __bf16* __restrict__ Bt,  // [N,K]
    const float* __restrict__ bias, // [N]
    float* __restrict__ C,          // [M,N]
    int M, int N, int K)
{
    __shared__ __align__(16) __bf16 As[64 * 32];
    __shared__ __align__(16) __bf16 Bs[64 * 32];

    const int tid  = threadIdx.x;
    const int lane = tid & 63;
    const int wave = tid >> 6;
    const int wm = (wave >> 1) * 32;
    const int wn = (wave & 1) * 32;
    const int m0 = blockIdx.y * 64;
    const int n0 = blockIdx.x * 64;
    const int lm = lane & 15;
    const int kq = lane >> 4;

    f32x4 acc[2][2] = {};

    for (int k0 = 0; k0 < K; k0 += 32) {
        __syncthreads();
        {
            int row = tid >> 2;              // 0..63
            int off = (tid & 3) * 16;
            const char* ga = (const char*)(A + (size_t)(m0 + row) * K + k0) + off;
            char* la = (char*)As + tid * 16;
            __builtin_amdgcn_global_load_lds(
                (const __attribute__((address_space(1))) void*)ga,
                (__attribute__((address_space(3))) void*)la, 16, 0, 0);
            const char* gb = (const char*)(Bt + (size_t)(n0 + row) * K + k0) + off;
            char* lb = (char*)Bs + tid * 16;
            __builtin_amdgcn_global_load_lds(
                (const __attribute__((address_space(1))) void*)gb,
                (__attribute__((address_space(3))) void*)lb, 16, 0, 0);
        }
        __syncthreads();

        bf16x8 af[2], bf[2];
        #pragma unroll
        for (int t = 0; t < 2; t++) {
            af[t] = *(const bf16x8*)&As[(wm + t * 16 + lm) * 32 + kq * 8];
            bf[t] = *(const bf16x8*)&Bs[(wn + t * 16 + lm) * 32 + kq * 8];
        }
        #pragma unroll
        for (int i = 0; i < 2; i++)
            #pragma unroll
            for (int j = 0; j < 2; j++)
                acc[i][j] = __builtin_amdgcn_mfma_f32_16x16x32_bf16(
                    af[i], bf[j], acc[i][j], 0, 0, 0);
    }

    const int r0 = kq * 4;
    #pragma unroll
    for (int i = 0; i < 2; i++) {
        #pragma unroll
        for (int j = 0; j < 2; j++) {
            int col = n0 + wn + j * 16 + lm;
            float bv = bias[col];
            #pragma unroll
            for (int r = 0; r < 4; r++) {
                int row = m0 + wm + i * 16 + r0 + r;
                C[(size_t)row * N + col] = acc[i][j][r] + bv;
            }
        }
    }
}

// ---------------------------------------------------------------------------
// K-parallel MFMA flash attention (causal), bf16 in/out, fp32 accum.
// Block = 256 threads = 4 waves; block owns 64 q-rows (4 frags/wave).
// Wave w processes k-tiles t = w, w+4, ... INDEPENDENTLY (no barriers in the
// k-loop) accumulating private unnormalized (O, l) — additive because the
// softmax has no running max (p = exp2(s), s pre-scaled by log2e/8, clamp).
// [Round 6: verbatim revert to the round-1 version — best measured 52.5 µs,
//  VGPR 80 -> ~4 waves/SIMD. The 32x32 in-register-P redesign (r4/r5) cut
//  bank conflicts 8x but cost half the residency: net slower.]
//
// QK^T is computed SWAPPED: S^T = mfma(K_frag, Q_frag), so each lane holds
// P[q=c][k = jj*16 + quad*4 + r] — 4 CONSECUTIVE k of one q-row. These pack
// into one aligned 8-byte LDS store per (jj,qf) that lands exactly in the
// A-frag layout the PV readback needs (bank-uniform). Row-sums of l are
// lane-local + 2 cross-quad shuffles.
// End: 3-barrier LDS tree combine of the 4 waves' partials, then normalize.
// ---------------------------------------------------------------------------
__global__ __launch_bounds__(256) void attn_kpar_mfma(
    const __bf16* __restrict__ qkv, const __bf16* __restrict__ vt,
    __bf16* __restrict__ attn)
{
    // smem: loop phase = Pbuf[4 waves][4 qf][2048 B] = 32768 B
    //       combine    = Ored[2][64][66] f32 (33792 B) + lred[2][64] (512 B)
    __shared__ __align__(16) char smem[34304];

    const int tid  = threadIdx.x;
    const int wave = tid >> 6;
    const int lane = tid & 63;
    const int quad = lane >> 4;
    const int c    = lane & 15;

    const int bh = blockIdx.x;
    const int b  = bh >> 4;
    const int h  = bh & 15;
    const int qblk = (int)(gridDim.y - 1) - blockIdx.y;   // heavy first
    const int q0 = qblk * 64;

    const size_t base = (size_t)b * SEQ * QKV3;
    const int hoff = h * HDIM;
    const __bf16* vbase = vt + (size_t)bh * 64 * SEQ;

    // Q B-frags (pre-scaled by log2(e)/8 in the QKV GEMM epilogue)
    bf16x8 aq[4][2];
    #pragma unroll
    for (int qf = 0; qf < 4; qf++) {
        const __bf16* qrow = qkv + base +
            (size_t)(q0 + qf * 16 + c) * QKV3 + hoff + quad * 8;
        aq[qf][0] = *(const bf16x8*)(qrow);
        aq[qf][1] = *(const bf16x8*)(qrow + 32);
    }

    f32x4 acc[4][4] = {};      // [qf][dd], C-layout: col=d (lane&15), row=q (quad*4+r)
    float lpart[4] = {};       // per-lane row-sum partial for q = c (per qf)

    char* pbw = smem + wave * 8192;
    const int ntiles = qblk + 1;    // 64-k tiles covering [0, q0+63]

    for (int t = wave; t < ntiles; t += 4) {
        const int k0 = t * 64;
        const bool diag = (t == ntiles - 1);

        // S^T = K Q^T per jj (16 k-rows), exp2, pack 4 bf16 -> one b64 store
        #pragma unroll
        for (int jj = 0; jj < 4; jj++) {
            const __bf16* krow = qkv + base +
                (size_t)(k0 + jj * 16 + c) * QKV3 + EMBD + hoff + quad * 8;
            bf16x8 bk0 = *(const bf16x8*)(krow);
            bf16x8 bk1 = *(const bf16x8*)(krow + 32);
            const int kb = k0 + jj * 16 + quad * 4;   // this lane's k base (4 r's)
            const int wb = (jj >> 1) * 1024 + (((jj & 1) * 2 + (quad >> 1))) * 256
                         + c * 16 + (quad & 1) * 8;
            #pragma unroll
            for (int qf = 0; qf < 4; qf++) {
                f32x4 s = {};
                s = __builtin_amdgcn_mfma_f32_16x16x32_bf16(bk0, aq[qf][0], s, 0, 0, 0);
                s = __builtin_amdgcn_mfma_f32_16x16x32_bf16(bk1, aq[qf][1], s, 0, 0, 0);
                const int qa = q0 + qf * 16 + c;
                bf16x4 pk;
                #pragma unroll
                for (int r = 0; r < 4; r++) {
                    float p;
                    if (diag && (kb + r > qa)) p = 0.f;
                    else p = fast_exp2(fminf(s[r], SCLAMP));
                    lpart[qf] += p;
                    pk[r] = (__bf16)p;
                }
                *(bf16x4*)(pbw + qf * 2048 + wb) = pk;
            }
        }

        // O += P V : P A-frags from wave-private LDS (in-order per-wave pipe),
        // V^T B-frags direct from vt. Split by 32-k chunk to cap VGPR pressure.
        __builtin_amdgcn_s_setprio(1);
        #pragma unroll
        for (int kc = 0; kc < 2; kc++) {
            bf16x8 ap[4];
            #pragma unroll
            for (int qf = 0; qf < 4; qf++)
                ap[qf] = *(const bf16x8*)(pbw + qf * 2048 + kc * 1024 + lane * 16);
            #pragma unroll
            for (int dd = 0; dd < 4; dd++) {
                const __bf16* vr = vbase + (size_t)(dd * 16 + c) * SEQ
                                 + k0 + kc * 32 + quad * 8;
                bf16x8 bv = *(const bf16x8*)(vr);
                #pragma unroll
                for (int qf = 0; qf < 4; qf++)
                    acc[qf][dd] = __builtin_amdgcn_mfma_f32_16x16x32_bf16(
                        ap[qf], bv, acc[qf][dd], 0, 0, 0);
            }
        }
        __builtin_amdgcn_s_setprio(0);
    }

    // Full row-sums of l within wave: lane holds q=c partial; reduce across quads
    #pragma unroll
    for (int qf = 0; qf < 4; qf++) {
        float v = lpart[qf];
        v += __shfl_xor(v, 16);
        v += __shfl_xor(v, 32);
        lpart[qf] = v;
    }

    __syncthreads();   // done with Pbuf; reuse smem for the combine

    float* Ored = (float*)smem;                    // [2][64][66]
    float* lred = (float*)(smem + 33792);          // [2][64]

    if (wave < 2) {
        float* R = Ored + wave * (64 * 66);
        #pragma unroll
        for (int qf = 0; qf < 4; qf++) {
            #pragma unroll
            for (int dd = 0; dd < 4; dd++)
                #pragma unroll
                for (int r = 0; r < 4; r++)
                    R[(qf * 16 + quad * 4 + r) * 66 + dd * 16 + c] = acc[qf][dd][r];
            if (quad == 0) lred[wave * 64 + qf * 16 + c] = lpart[qf];
        }
    }
    __syncthreads();
    if (wave >= 2) {
        float* R = Ored + (wave - 2) * (64 * 66);
        #pragma unroll
        for (int qf = 0; qf < 4; qf++) {
            #pragma unroll
            for (int dd = 0; dd < 4; dd++)
                #pragma unroll
                for (int r = 0; r < 4; r++)
                    R[(qf * 16 + quad * 4 + r) * 66 + dd * 16 + c] += acc[qf][dd][r];
            if (quad == 0) lred[(wave - 2) * 64 + qf * 16 + c] += lpart[qf];
        }
    }
    __syncthreads();

    // Final: each thread does one 8-col chunk of one row; 2 iterations for 64 rows
    #pragma unroll
    for (int it = 0; it < 2; it++) {
        const int flat = it * 256 + tid;
        const int row = flat >> 3;         // 0..63
        const int cg  = flat & 7;          // 8-col group
        const float l = lred[row] + lred[64 + row];
        const float inv = 1.f / l;
        const float* R0 = Ored + row * 66 + cg * 8;
        const float* R1 = R0 + 64 * 66;
        bf16x8 o;
        #pragma unroll
        for (int i = 0; i < 8; i++) o[i] = (__bf16)((R0[i] + R1[i]) * inv);
        *(bf16x8*)&attn[((size_t)b * SEQ + q0 + row) * EMBD + hoff + cg * 8] = o;
    }
}

// ---------------------------------------------------------------------------
extern "C" void kernel_launch(void* const* d_in, const int* in_sizes, int n_in,
                              void* d_out, int out_size, void* d_ws, size_t ws_size,
                              hipStream_t stream)
{
    const float* x     = (const float*)d_in[0];  // [2,2048,1024]
    const float* W_qkv = (const float*)d_in[1];  // [1024,3072]
    const float* b_qkv = (const float*)d_in[2];  // [3072]
    const float* W_out = (const float*)d_in[3];  // [1024,1024]
    const float* b_out = (const float*)d_in[4];  // [1024]
    float* out = (float*)d_out;                  // [2,2048,1024] fp32

    const int M = BATCH * SEQ;   // 4096

    __bf16* xbf    = (__bf16*)d_ws;                          // [4096,1024]  8 MB
    __bf16* Wqkv_t = xbf    + (size_t)M * EMBD;              // [3072,1024]  6 MB
    __bf16* Wout_t = Wqkv_t + (size_t)QKV3 * EMBD;           // [1024,1024]  2 MB
    __bf16* qkv    = Wout_t + (size_t)EMBD * EMBD;           // [4096,3072] 24 MB
    __bf16* attn   = qkv    + (size_t)M * QKV3;              // [4096,1024]  8 MB
    __bf16* vtbuf  = attn   + (size_t)M * EMBD;              // [32,64,2048]  8 MB

    // 0) Casts
    cast_f32_bf16<<<(M * EMBD) / (256 * 8), 256, 0, stream>>>(x, xbf);
    {
        dim3 g(QKV3 / 64, EMBD / 64);
        transpose_cast_bf16<<<g, 256, 0, stream>>>(W_qkv, Wqkv_t, EMBD, QKV3);
    }
    {
        dim3 g(EMBD / 64, EMBD / 64);
        transpose_cast_bf16<<<g, 256, 0, stream>>>(W_out, Wout_t, EMBD, EMBD);
    }
    // 1) QKV projection (bf16 out; Q columns pre-scaled by log2(e)/8)
    {
        dim3 grid(QKV3 / 128, M / 128);
        gemm_bt_mfma<true><<<grid, 256, 0, stream>>>(xbf, Wqkv_t, b_qkv, qkv, M, QKV3, EMBD, EMBD);
    }
    // 1b) Pre-transpose V to [bh][d][k]
    {
        dim3 grid(SEQ / 64, BATCH * NHEAD);
        transpose_v_bf16<<<grid, 256, 0, stream>>>(qkv, vtbuf);
    }
    // 2) K-parallel MFMA flash causal attention (64 q/block, no loop barriers)
    {
        dim3 grid(BATCH * NHEAD, SEQ / 64);
        attn_kpar_mfma<<<grid, 256, 0, stream>>>(qkv, vtbuf, attn);
    }
    // 3) Output projection (fp32 out): 64x64 tiles -> 1024 blocks = 4/CU
    {
        dim3 grid(EMBD / 64, M / 64);
        gemm_bt_mfma64<<<grid, 256, 0, stream>>>(attn, Wout_t, b_out, out, M, EMBD, EMBD);
    }
}

// Round 7
// 194.309 us; speedup vs baseline: 1.2003x; 1.0175x over previous
//
#include <hip/hip_runtime.h>
#include <hip/hip_bf16.h>

// Problem constants
#define BATCH 2
#define SEQ   2048
#define EMBD  1024
#define NHEAD 16
#define HDIM  64
#define QKV3  (3 * EMBD)   // 3072

// Q pre-scale folded into the QKV GEMM epilogue: (1/sqrt(HDIM)) * log2(e)
// so attention can use hardware exp2 directly (v_exp_f32 is 2^x).
#define QSCALE 0.18033688011112042f
// clamp for exp2 argument = 60 * log2(e)  (same guard as old exp clamp 60)
#define SCLAMP 86.56f

typedef __attribute__((ext_vector_type(8))) __bf16 bf16x8;
typedef __attribute__((ext_vector_type(4))) __bf16 bf16x4;
typedef __attribute__((ext_vector_type(4))) float f32x4;

__device__ __forceinline__ float fast_exp2(float x) {
#if __has_builtin(__builtin_amdgcn_exp2f)
    return __builtin_amdgcn_exp2f(x);
#else
    return exp2f(x);
#endif
}

// ---------------------------------------------------------------------------
// fp32 -> bf16 elementwise cast (8 elems/thread)
// ---------------------------------------------------------------------------
__global__ __launch_bounds__(256) void cast_f32_bf16(
    const float* __restrict__ in, __bf16* __restrict__ out)
{
    int i = (blockIdx.x * 256 + threadIdx.x) * 8;
    float4 a = *(const float4*)&in[i];
    float4 b = *(const float4*)&in[i + 4];
    bf16x8 o;
    o[0] = (__bf16)a.x; o[1] = (__bf16)a.y; o[2] = (__bf16)a.z; o[3] = (__bf16)a.w;
    o[4] = (__bf16)b.x; o[5] = (__bf16)b.y; o[6] = (__bf16)b.z; o[7] = (__bf16)b.w;
    *(bf16x8*)&out[i] = o;
}

// ---------------------------------------------------------------------------
// fp32 [K,N] -> bf16 [N,K] transpose+cast, 64x64 LDS tile, 256 threads
// ---------------------------------------------------------------------------
__global__ __launch_bounds__(256) void transpose_cast_bf16(
    const float* __restrict__ in, __bf16* __restrict__ out, int K, int N)
{
    __shared__ float t[64][65];
    const int k0 = blockIdx.y * 64, n0 = blockIdx.x * 64;
    const int tid = threadIdx.x;
    #pragma unroll
    for (int p = 0; p < 4; p++) {
        int kr = p * 16 + (tid >> 4);
        int c4 = (tid & 15) * 4;
        float4 v = *(const float4*)&in[(size_t)(k0 + kr) * N + n0 + c4];
        t[kr][c4] = v.x; t[kr][c4 + 1] = v.y; t[kr][c4 + 2] = v.z; t[kr][c4 + 3] = v.w;
    }
    __syncthreads();
    #pragma unroll
    for (int p = 0; p < 4; p++) {
        int nr = p * 16 + (tid >> 4);
        int k4 = (tid & 15) * 4;
        bf16x4 o;
        o[0] = (__bf16)t[k4 + 0][nr];
        o[1] = (__bf16)t[k4 + 1][nr];
        o[2] = (__bf16)t[k4 + 2][nr];
        o[3] = (__bf16)t[k4 + 3][nr];
        *(bf16x4*)&out[(size_t)(n0 + nr) * K + k0 + k4] = o;
    }
}

// ---------------------------------------------------------------------------
// bf16 MFMA GEMM (B^T form): C[M,N] = A[M,K] @ Bt[N,K]^T + bias[N]
// 128x128 block tile, 4 waves (2x2), mfma_f32_16x16x32_bf16, BK=32,
// global_load_lds width-16 staging. Columns < nscale get *QSCALE.
// Round 7:
//  * XCD-chunk swizzle (T1, bijective; requires gridDim.x % 8 == 0): each
//    XCD owns gridDim.x/8 contiguous n-tiles -> its B-chunk is L2-resident
//    (768 KB for QKV vs 6 MB through L3), and co-resident same-m blocks
//    share one A-panel in L2.
//  * Fused V-transpose: for col >= 2*EMBD (V region), write vt[bh][d][k]
//    directly (4 consecutive rows -> one aligned 8B store) and SKIP the
//    qkv write — replaces the separate transpose_v kernel entirely.
// ---------------------------------------------------------------------------
template<bool OUT_BF16>
__global__ __launch_bounds__(256) void gemm_bt_mfma(
    const __bf16* __restrict__ A,   // [M,K]
    const __bf16* __restrict__ Bt,  // [N,K]
    const float* __restrict__ bias, // [N]
    void* __restrict__ Cv,          // [M,N]
    __bf16* __restrict__ vt,        // fused V^T out (nullptr = disabled)
    int M, int N, int K, int nscale)
{
    __shared__ __align__(16) __bf16 As[128 * 32];
    __shared__ __align__(16) __bf16 Bs[128 * 32];

    const int tid  = threadIdx.x;
    const int lane = tid & 63;
    const int wave = tid >> 6;
    const int wm = (wave >> 1) * 64;
    const int wn = (wave & 1) * 64;

    // XCD-chunk swizzle: hw%8 = XCD (round-robin dispatch). Give XCD x the
    // n-tile range [x*cpx, (x+1)*cpx); consecutive i within an XCD share m.
    const int hw  = (int)(blockIdx.x + gridDim.x * blockIdx.y);
    const int cpx = (int)gridDim.x >> 3;
    const int xcd = hw & 7;
    const int i_  = hw >> 3;
    const int n0 = (xcd * cpx + (i_ % cpx)) * 128;
    const int m0 = (i_ / cpx) * 128;

    const int lm = lane & 15;
    const int kq = lane >> 4;

    f32x4 acc[4][4] = {};

    for (int k0 = 0; k0 < K; k0 += 32) {
        __syncthreads();
        #pragma unroll
        for (int r = 0; r < 2; r++) {
            int flat = r * 256 + tid;
            int row  = flat >> 2;
            int off  = (flat & 3) * 16;
            const char* ga = (const char*)(A + (size_t)(m0 + row) * K + k0) + off;
            char* la = (char*)As + flat * 16;
            __builtin_amdgcn_global_load_lds(
                (const __attribute__((address_space(1))) void*)ga,
                (__attribute__((address_space(3))) void*)la, 16, 0, 0);
            const char* gb = (const char*)(Bt + (size_t)(n0 + row) * K + k0) + off;
            char* lb = (char*)Bs + flat * 16;
            __builtin_amdgcn_global_load_lds(
                (const __attribute__((address_space(1))) void*)gb,
                (__attribute__((address_space(3))) void*)lb, 16, 0, 0);
        }
        __syncthreads();

        bf16x8 af[4], bf[4];
        #pragma unroll
        for (int t = 0; t < 4; t++) {
            af[t] = *(const bf16x8*)&As[(wm + t * 16 + lm) * 32 + kq * 8];
            bf[t] = *(const bf16x8*)&Bs[(wn + t * 16 + lm) * 32 + kq * 8];
        }
        #pragma unroll
        for (int i = 0; i < 4; i++)
            #pragma unroll
            for (int j = 0; j < 4; j++)
                acc[i][j] = __builtin_amdgcn_mfma_f32_16x16x32_bf16(
                    af[i], bf[j], acc[i][j], 0, 0, 0);
    }

    const int r0 = kq * 4;
    #pragma unroll
    for (int i = 0; i < 4; i++) {
        #pragma unroll
        for (int j = 0; j < 4; j++) {
            int col = n0 + wn + j * 16 + lm;
            float bv = bias[col];
            float sc = (col < nscale) ? QSCALE : 1.0f;
            if (OUT_BF16 && vt && col >= 2 * EMBD) {
                // V region: write vt[bh][d][k] only (skip qkv)
                const int hd   = col - 2 * EMBD;        // h*64 + d
                const int rowb = m0 + wm + i * 16 + r0; // 4 consecutive rows
                const int bh   = (rowb >> 11) * 16 + (hd >> 6);
                const int d    = hd & 63;
                const int seq  = rowb & (SEQ - 1);
                bf16x4 o;
                #pragma unroll
                for (int r = 0; r < 4; r++) o[r] = (__bf16)(acc[i][j][r] + bv);
                *(bf16x4*)&vt[((size_t)bh * 64 + d) * SEQ + seq] = o;
            } else {
                #pragma unroll
                for (int r = 0; r < 4; r++) {
                    int row = m0 + wm + i * 16 + r0 + r;
                    float val = (acc[i][j][r] + bv) * sc;
                    if (OUT_BF16) ((__bf16*)Cv)[(size_t)row * N + col] = (__bf16)val;
                    else          ((float*)Cv)[(size_t)row * N + col] = val;
                }
            }
        }
    }
}

// ---------------------------------------------------------------------------
// Small-tile bf16 MFMA GEMM for the output projection: C = A @ Bt^T + bias,
// fp32 out. 64x64 block tile, 4 waves (2x2, 32x32 each), BK=32.
// 1024 blocks = 4 blocks/CU. Round 7: + XCD-chunk swizzle (B-chunk 256 KB
// per XCD stays L2-resident; paired blocks share the A m-panel).
// ---------------------------------------------------------------------------
__global__ __launch_bounds__(256) void gemm_bt_mfma64(
    const __bf16* __restrict__ A,   // [M,K]
    const __bf16* __restrict__ Bt,  // [N,K]
    const float* __restrict__ bias, // [N]
    float* __restrict__ C,          // [M,N]
    int M, int N, int K)
{
    __shared__ __align__(16) __bf16 As[64 * 32];
    __shared__ __align__(16) __bf16 Bs[64 * 32];

    const int tid  = threadIdx.x;
    const int lane = tid & 63;
    const int wave = tid >> 6;
    const int wm = (wave >> 1) * 32;
    const int wn = (wave & 1) * 32;

    const int hw  = (int)(blockIdx.x + gridDim.x * blockIdx.y);
    const int cpx = (int)gridDim.x >> 3;
    const int xcd = hw & 7;
    const int i_  = hw >> 3;
    const int n0 = (xcd * cpx + (i_ % cpx)) * 64;
    const int m0 = (i_ / cpx) * 64;

    const int lm = lane & 15;
    const int kq = lane >> 4;

    f32x4 acc[2][2] = {};

    for (int k0 = 0; k0 < K; k0 += 32) {
        __syncthreads();
        {
            int row = tid >> 2;              // 0..63
            int off = (tid & 3) * 16;
            const char* ga = (const char*)(A + (size_t)(m0 + row) * K + k0) + off;
            char* la = (char*)As + tid * 16;
            __builtin_amdgcn_global_load_lds(
                (const __attribute__((address_space(1))) void*)ga,
                (__attribute__((address_space(3))) void*)la, 16, 0, 0);
            const char* gb = (const char*)(Bt + (size_t)(n0 + row) * K + k0) + off;
            char* lb = (char*)Bs + tid * 16;
            __builtin_amdgcn_global_load_lds(
                (const __attribute__((address_space(1))) void*)gb,
                (__attribute__((address_space(3))) void*)lb, 16, 0, 0);
        }
        __syncthreads();

        bf16x8 af[2], bf[2];
        #pragma unroll
        for (int t = 0; t < 2; t++) {
            af[t] = *(const bf16x8*)&As[(wm + t * 16 + lm) * 32 + kq * 8];
            bf[t] = *(const bf16x8*)&Bs[(wn + t * 16 + lm) * 32 + kq * 8];
        }
        #pragma unroll
        for (int i = 0; i < 2; i++)
            #pragma unroll
            for (int j = 0; j < 2; j++)
                acc[i][j] = __builtin_amdgcn_mfma_f32_16x16x32_bf16(
                    af[i], bf[j], acc[i][j], 0, 0, 0);
    }

    const int r0 = kq * 4;
    #pragma unroll
    for (int i = 0; i < 2; i++) {
        #pragma unroll
        for (int j = 0; j < 2; j++) {
            int col = n0 + wn + j * 16 + lm;
            float bv = bias[col];
            #pragma unroll
            for (int r = 0; r < 4; r++) {
                int row = m0 + wm + i * 16 + r0 + r;
                C[(size_t)row * N + col] = acc[i][j][r] + bv;
            }
        }
    }
}

// ---------------------------------------------------------------------------
// K-parallel MFMA flash attention (causal), bf16 in/out, fp32 accum.
// Block = 256 threads = 4 waves; block owns 64 q-rows (4 frags/wave).
// Wave w processes k-tiles t = w, w+4, ... INDEPENDENTLY (no barriers in the
// k-loop) accumulating private unnormalized (O, l) — additive because the
// softmax has no running max (p = exp2(s), s pre-scaled by log2e/8, clamp).
// [Round 7: UNCHANGED control — best measured structure, 52.5-53.5 µs.
//  Occupancy here is block-count-limited (1024 blocks = 4/CU capacity);
//  finer blocks double K/V L2 traffic toward the per-XCD ceiling.]
//
// QK^T is computed SWAPPED: S^T = mfma(K_frag, Q_frag), so each lane holds
// P[q=c][k = jj*16 + quad*4 + r] — 4 CONSECUTIVE k of one q-row. These pack
// into one aligned 8-byte LDS store per (jj,qf) that lands exactly in the
// A-frag layout the PV readback needs (bank-uniform). Row-sums of l are
// lane-local + 2 cross-quad shuffles.
// End: 3-barrier LDS tree combine of the 4 waves' partials, then normalize.
// ---------------------------------------------------------------------------
__global__ __launch_bounds__(256) void attn_kpar_mfma(
    const __bf16* __restrict__ qkv, const __bf16* __restrict__ vt,
    __bf16* __restrict__ attn)
{
    // smem: loop phase = Pbuf[4 waves][4 qf][2048 B] = 32768 B
    //       combine    = Ored[2][64][66] f32 (33792 B) + lred[2][64] (512 B)
    __shared__ __align__(16) char smem[34304];

    const int tid  = threadIdx.x;
    const int wave = tid >> 6;
    const int lane = tid & 63;
    const int quad = lane >> 4;
    const int c    = lane & 15;

    const int bh = blockIdx.x;
    const int b  = bh >> 4;
    const int h  = bh & 15;
    const int qblk = (int)(gridDim.y - 1) - blockIdx.y;   // heavy first
    const int q0 = qblk * 64;

    const size_t base = (size_t)b * SEQ * QKV3;
    const int hoff = h * HDIM;
    const __bf16* vbase = vt + (size_t)bh * 64 * SEQ;

    // Q B-frags (pre-scaled by log2(e)/8 in the QKV GEMM epilogue)
    bf16x8 aq[4][2];
    #pragma unroll
    for (int qf = 0; qf < 4; qf++) {
        const __bf16* qrow = qkv + base +
            (size_t)(q0 + qf * 16 + c) * QKV3 + hoff + quad * 8;
        aq[qf][0] = *(const bf16x8*)(qrow);
        aq[qf][1] = *(const bf16x8*)(qrow + 32);
    }

    f32x4 acc[4][4] = {};      // [qf][dd], C-layout: col=d (lane&15), row=q (quad*4+r)
    float lpart[4] = {};       // per-lane row-sum partial for q = c (per qf)

    char* pbw = smem + wave * 8192;
    const int ntiles = qblk + 1;    // 64-k tiles covering [0, q0+63]

    for (int t = wave; t < ntiles; t += 4) {
        const int k0 = t * 64;
        const bool diag = (t == ntiles - 1);

        // S^T = K Q^T per jj (16 k-rows), exp2, pack 4 bf16 -> one b64 store
        #pragma unroll
        for (int jj = 0; jj < 4; jj++) {
            const __bf16* krow = qkv + base +
                (size_t)(k0 + jj * 16 + c) * QKV3 + EMBD + hoff + quad * 8;
            bf16x8 bk0 = *(const bf16x8*)(krow);
            bf16x8 bk1 = *(const bf16x8*)(krow + 32);
            const int kb = k0 + jj * 16 + quad * 4;   // this lane's k base (4 r's)
            const int wb = (jj >> 1) * 1024 + (((jj & 1) * 2 + (quad >> 1))) * 256
                         + c * 16 + (quad & 1) * 8;
            #pragma unroll
            for (int qf = 0; qf < 4; qf++) {
                f32x4 s = {};
                s = __builtin_amdgcn_mfma_f32_16x16x32_bf16(bk0, aq[qf][0], s, 0, 0, 0);
                s = __builtin_amdgcn_mfma_f32_16x16x32_bf16(bk1, aq[qf][1], s, 0, 0, 0);
                const int qa = q0 + qf * 16 + c;
                bf16x4 pk;
                #pragma unroll
                for (int r = 0; r < 4; r++) {
                    float p;
                    if (diag && (kb + r > qa)) p = 0.f;
                    else p = fast_exp2(fminf(s[r], SCLAMP));
                    lpart[qf] += p;
                    pk[r] = (__bf16)p;
                }
                *(bf16x4*)(pbw + qf * 2048 + wb) = pk;
            }
        }

        // O += P V : P A-frags from wave-private LDS (in-order per-wave pipe),
        // V^T B-frags direct from vt. Split by 32-k chunk to cap VGPR pressure.
        __builtin_amdgcn_s_setprio(1);
        #pragma unroll
        for (int kc = 0; kc < 2; kc++) {
            bf16x8 ap[4];
            #pragma unroll
            for (int qf = 0; qf < 4; qf++)
                ap[qf] = *(const bf16x8*)(pbw + qf * 2048 + kc * 1024 + lane * 16);
            #pragma unroll
            for (int dd = 0; dd < 4; dd++) {
                const __bf16* vr = vbase + (size_t)(dd * 16 + c) * SEQ
                                 + k0 + kc * 32 + quad * 8;
                bf16x8 bv = *(const bf16x8*)(vr);
                #pragma unroll
                for (int qf = 0; qf < 4; qf++)
                    acc[qf][dd] = __builtin_amdgcn_mfma_f32_16x16x32_bf16(
                        ap[qf], bv, acc[qf][dd], 0, 0, 0);
            }
        }
        __builtin_amdgcn_s_setprio(0);
    }

    // Full row-sums of l within wave: lane holds q=c partial; reduce across quads
    #pragma unroll
    for (int qf = 0; qf < 4; qf++) {
        float v = lpart[qf];
        v += __shfl_xor(v, 16);
        v += __shfl_xor(v, 32);
        lpart[qf] = v;
    }

    __syncthreads();   // done with Pbuf; reuse smem for the combine

    float* Ored = (float*)smem;                    // [2][64][66]
    float* lred = (float*)(smem + 33792);          // [2][64]

    if (wave < 2) {
        float* R = Ored + wave * (64 * 66);
        #pragma unroll
        for (int qf = 0; qf < 4; qf++) {
            #pragma unroll
            for (int dd = 0; dd < 4; dd++)
                #pragma unroll
                for (int r = 0; r < 4; r++)
                    R[(qf * 16 + quad * 4 + r) * 66 + dd * 16 + c] = acc[qf][dd][r];
            if (quad == 0) lred[wave * 64 + qf * 16 + c] = lpart[qf];
        }
    }
    __syncthreads();
    if (wave >= 2) {
        float* R = Ored + (wave - 2) * (64 * 66);
        #pragma unroll
        for (int qf = 0; qf < 4; qf++) {
            #pragma unroll
            for (int dd = 0; dd < 4; dd++)
                #pragma unroll
                for (int r = 0; r < 4; r++)
                    R[(qf * 16 + quad * 4 + r) * 66 + dd * 16 + c] += acc[qf][dd][r];
            if (quad == 0) lred[(wave - 2) * 64 + qf * 16 + c] += lpart[qf];
        }
    }
    __syncthreads();

    // Final: each thread does one 8-col chunk of one row; 2 iterations for 64 rows
    #pragma unroll
    for (int it = 0; it < 2; it++) {
        const int flat = it * 256 + tid;
        const int row = flat >> 3;         // 0..63
        const int cg  = flat & 7;          // 8-col group
        const float l = lred[row] + lred[64 + row];
        const float inv = 1.f / l;
        const float* R0 = Ored + row * 66 + cg * 8;
        const float* R1 = R0 + 64 * 66;
        bf16x8 o;
        #pragma unroll
        for (int i = 0; i < 8; i++) o[i] = (__bf16)((R0[i] + R1[i]) * inv);
        *(bf16x8*)&attn[((size_t)b * SEQ + q0 + row) * EMBD + hoff + cg * 8] = o;
    }
}

// ---------------------------------------------------------------------------
extern "C" void kernel_launch(void* const* d_in, const int* in_sizes, int n_in,
                              void* d_out, int out_size, void* d_ws, size_t ws_size,
                              hipStream_t stream)
{
    const float* x     = (const float*)d_in[0];  // [2,2048,1024]
    const float* W_qkv = (const float*)d_in[1];  // [1024,3072]
    const float* b_qkv = (const float*)d_in[2];  // [3072]
    const float* W_out = (const float*)d_in[3];  // [1024,1024]
    const float* b_out = (const float*)d_in[4];  // [1024]
    float* out = (float*)d_out;                  // [2,2048,1024] fp32

    const int M = BATCH * SEQ;   // 4096

    __bf16* xbf    = (__bf16*)d_ws;                          // [4096,1024]  8 MB
    __bf16* Wqkv_t = xbf    + (size_t)M * EMBD;              // [3072,1024]  6 MB
    __bf16* Wout_t = Wqkv_t + (size_t)QKV3 * EMBD;           // [1024,1024]  2 MB
    __bf16* qkv    = Wout_t + (size_t)EMBD * EMBD;           // [4096,3072] 24 MB
    __bf16* attn   = qkv    + (size_t)M * QKV3;              // [4096,1024]  8 MB
    __bf16* vtbuf  = attn   + (size_t)M * EMBD;              // [32,64,2048]  8 MB

    // 0) Casts
    cast_f32_bf16<<<(M * EMBD) / (256 * 8), 256, 0, stream>>>(x, xbf);
    {
        dim3 g(QKV3 / 64, EMBD / 64);
        transpose_cast_bf16<<<g, 256, 0, stream>>>(W_qkv, Wqkv_t, EMBD, QKV3);
    }
    {
        dim3 g(EMBD / 64, EMBD / 64);
        transpose_cast_bf16<<<g, 256, 0, stream>>>(W_out, Wout_t, EMBD, EMBD);
    }
    // 1) QKV projection (bf16 out; Q cols pre-scaled; V region written
    //    straight to vt[bh][d][k] — transpose_v kernel eliminated)
    {
        dim3 grid(QKV3 / 128, M / 128);   // 24 x 32 = 768 blocks (%8 == 0)
        gemm_bt_mfma<true><<<grid, 256, 0, stream>>>(
            xbf, Wqkv_t, b_qkv, qkv, vtbuf, M, QKV3, EMBD, EMBD);
    }
    // 2) K-parallel MFMA flash causal attention (64 q/block, no loop barriers)
    {
        dim3 grid(BATCH * NHEAD, SEQ / 64);
        attn_kpar_mfma<<<grid, 256, 0, stream>>>(qkv, vtbuf, attn);
    }
    // 3) Output projection (fp32 out): 64x64 tiles, XCD-chunk swizzled
    {
        dim3 grid(EMBD / 64, M / 64);     // 16 x 64 = 1024 blocks (%8 == 0)
        gemm_bt_mfma64<<<grid, 256, 0, stream>>>(attn, Wout_t, b_out, out, M, EMBD, EMBD);
    }
}

// Round 8
// 186.550 us; speedup vs baseline: 1.2502x; 1.0416x over previous
//
#include <hip/hip_runtime.h>
#include <hip/hip_bf16.h>

// Problem constants
#define BATCH 2
#define SEQ   2048
#define EMBD  1024
#define NHEAD 16
#define HDIM  64
#define QKV3  (3 * EMBD)   // 3072

// Q pre-scale folded into the QKV GEMM epilogue: (1/sqrt(HDIM)) * log2(e)
// so attention can use hardware exp2 directly (v_exp_f32 is 2^x).
#define QSCALE 0.18033688011112042f
// clamp for exp2 argument = 60 * log2(e)  (same guard as old exp clamp 60)
#define SCLAMP 86.56f

typedef __attribute__((ext_vector_type(8))) __bf16 bf16x8;
typedef __attribute__((ext_vector_type(4))) __bf16 bf16x4;
typedef __attribute__((ext_vector_type(4))) float f32x4;

__device__ __forceinline__ float fast_exp2(float x) {
#if __has_builtin(__builtin_amdgcn_exp2f)
    return __builtin_amdgcn_exp2f(x);
#else
    return exp2f(x);
#endif
}

// ---------------------------------------------------------------------------
// Fused prep: one dispatch for (a) x fp32->bf16 cast, (b) W_qkv transpose+
// cast, (c) W_out transpose+cast. Grid partition:
//   blocks [0,2048)        : cast (8 elems/thread)
//   blocks [2048,2816)     : W_qkv 64x64 transpose tiles (48 x 16)
//   blocks [2816,3072)     : W_out 64x64 transpose tiles (16 x 16)
// Saves two kernel launches; the three parts are independent.
// ---------------------------------------------------------------------------
__global__ __launch_bounds__(256) void prep_fused(
    const float* __restrict__ x,    __bf16* __restrict__ xbf,
    const float* __restrict__ Wqkv, __bf16* __restrict__ Wqkv_t,
    const float* __restrict__ Wout, __bf16* __restrict__ Wout_t)
{
    const int bid = blockIdx.x;
    const int tid = threadIdx.x;

    if (bid < 2048) {
        int i = (bid * 256 + tid) * 8;
        float4 a = *(const float4*)&x[i];
        float4 b = *(const float4*)&x[i + 4];
        bf16x8 o;
        o[0] = (__bf16)a.x; o[1] = (__bf16)a.y; o[2] = (__bf16)a.z; o[3] = (__bf16)a.w;
        o[4] = (__bf16)b.x; o[5] = (__bf16)b.y; o[6] = (__bf16)b.z; o[7] = (__bf16)b.w;
        *(bf16x8*)&xbf[i] = o;
        return;
    }

    __shared__ float t[64][65];
    const float* in; __bf16* out; int N, n0, k0;
    if (bid < 2816) {
        int tile = bid - 2048;             // W_qkv [1024,3072]: 48 n-tiles x 16 k-tiles
        N = QKV3;
        n0 = (tile % 48) * 64; k0 = (tile / 48) * 64;
        in = Wqkv; out = Wqkv_t;
    } else {
        int tile = bid - 2816;             // W_out [1024,1024]: 16 x 16
        N = EMBD;
        n0 = (tile & 15) * 64; k0 = (tile >> 4) * 64;
        in = Wout; out = Wout_t;
    }
    const int K = EMBD;
    #pragma unroll
    for (int p = 0; p < 4; p++) {
        int kr = p * 16 + (tid >> 4);
        int c4 = (tid & 15) * 4;
        float4 v = *(const float4*)&in[(size_t)(k0 + kr) * N + n0 + c4];
        t[kr][c4] = v.x; t[kr][c4 + 1] = v.y; t[kr][c4 + 2] = v.z; t[kr][c4 + 3] = v.w;
    }
    __syncthreads();
    #pragma unroll
    for (int p = 0; p < 4; p++) {
        int nr = p * 16 + (tid >> 4);
        int k4 = (tid & 15) * 4;
        bf16x4 o;
        o[0] = (__bf16)t[k4 + 0][nr];
        o[1] = (__bf16)t[k4 + 1][nr];
        o[2] = (__bf16)t[k4 + 2][nr];
        o[3] = (__bf16)t[k4 + 3][nr];
        *(bf16x4*)&out[(size_t)(n0 + nr) * K + k0 + k4] = o;
    }
}

// ---------------------------------------------------------------------------
// bf16 MFMA GEMM (B^T form): C[M,N] = A[M,K] @ Bt[N,K]^T + bias[N]
// 128x128 block tile, 4 waves (2x2), mfma_f32_16x16x32_bf16.
// Round 8: BK=64 — halves the vmcnt-drain + barrier pairs per tile (the
// structural per-K-step stall). LDS is plane-split [kk][128][32] to keep the
// proven 64B row-stride bank pattern; achieved by pre-swizzling the per-lane
// GLOBAL source while the LDS dest stays linear (global_load_lds rule).
// XCD-chunk swizzle kept; fused V-transpose epilogue kept (writes V region
// straight to vt[bh][d][k], skipping the qkv store).
// ---------------------------------------------------------------------------
template<bool OUT_BF16>
__global__ __launch_bounds__(256) void gemm_bt_mfma(
    const __bf16* __restrict__ A,   // [M,K]
    const __bf16* __restrict__ Bt,  // [N,K]
    const float* __restrict__ bias, // [N]
    void* __restrict__ Cv,          // [M,N]
    __bf16* __restrict__ vt,        // fused V^T out (nullptr = disabled)
    int M, int N, int K, int nscale)
{
    __shared__ __align__(16) __bf16 As[2 * 128 * 32];   // [kk][row][32]
    __shared__ __align__(16) __bf16 Bs[2 * 128 * 32];

    const int tid  = threadIdx.x;
    const int lane = tid & 63;
    const int wave = tid >> 6;
    const int wm = (wave >> 1) * 64;
    const int wn = (wave & 1) * 64;

    // XCD-chunk swizzle (requires gridDim.x % 8 == 0)
    const int hw  = (int)(blockIdx.x + gridDim.x * blockIdx.y);
    const int cpx = (int)gridDim.x >> 3;
    const int xcd = hw & 7;
    const int i_  = hw >> 3;
    const int n0 = (xcd * cpx + (i_ % cpx)) * 128;
    const int m0 = (i_ / cpx) * 128;

    const int lm = lane & 15;
    const int kq = lane >> 4;

    f32x4 acc[4][4] = {};

    for (int k0 = 0; k0 < K; k0 += 64) {
        __syncthreads();
        #pragma unroll
        for (int r = 0; r < 4; r++) {
            int flat = r * 256 + tid;            // 0..1023
            int kk   = flat >> 9;                // k-half plane
            int row  = (flat >> 2) & 127;
            int c4   = flat & 3;                 // 16B chunk within 32-col plane
            const char* ga = (const char*)(A + (size_t)(m0 + row) * K
                                             + k0 + kk * 32 + c4 * 8);
            char* la = (char*)As + flat * 16;    // linear dest = [kk][row][c4]
            __builtin_amdgcn_global_load_lds(
                (const __attribute__((address_space(1))) void*)ga,
                (__attribute__((address_space(3))) void*)la, 16, 0, 0);
            const char* gb = (const char*)(Bt + (size_t)(n0 + row) * K
                                              + k0 + kk * 32 + c4 * 8);
            char* lb = (char*)Bs + flat * 16;
            __builtin_amdgcn_global_load_lds(
                (const __attribute__((address_space(1))) void*)gb,
                (__attribute__((address_space(3))) void*)lb, 16, 0, 0);
        }
        __syncthreads();

        #pragma unroll
        for (int kk = 0; kk < 2; kk++) {
            bf16x8 af[4], bf[4];
            #pragma unroll
            for (int t = 0; t < 4; t++) {
                af[t] = *(const bf16x8*)&As[kk * 4096 + (wm + t * 16 + lm) * 32 + kq * 8];
                bf[t] = *(const bf16x8*)&Bs[kk * 4096 + (wn + t * 16 + lm) * 32 + kq * 8];
            }
            #pragma unroll
            for (int i = 0; i < 4; i++)
                #pragma unroll
                for (int j = 0; j < 4; j++)
                    acc[i][j] = __builtin_amdgcn_mfma_f32_16x16x32_bf16(
                        af[i], bf[j], acc[i][j], 0, 0, 0);
        }
    }

    const int r0 = kq * 4;
    #pragma unroll
    for (int i = 0; i < 4; i++) {
        #pragma unroll
        for (int j = 0; j < 4; j++) {
            int col = n0 + wn + j * 16 + lm;
            float bv = bias[col];
            float sc = (col < nscale) ? QSCALE : 1.0f;
            if (OUT_BF16 && vt && col >= 2 * EMBD) {
                // V region: write vt[bh][d][k] only (skip qkv)
                const int hd   = col - 2 * EMBD;        // h*64 + d
                const int rowb = m0 + wm + i * 16 + r0; // 4 consecutive rows
                const int bh   = (rowb >> 11) * 16 + (hd >> 6);
                const int d    = hd & 63;
                const int seq  = rowb & (SEQ - 1);
                bf16x4 o;
                #pragma unroll
                for (int r = 0; r < 4; r++) o[r] = (__bf16)(acc[i][j][r] + bv);
                *(bf16x4*)&vt[((size_t)bh * 64 + d) * SEQ + seq] = o;
            } else {
                #pragma unroll
                for (int r = 0; r < 4; r++) {
                    int row = m0 + wm + i * 16 + r0 + r;
                    float val = (acc[i][j][r] + bv) * sc;
                    if (OUT_BF16) ((__bf16*)Cv)[(size_t)row * N + col] = (__bf16)val;
                    else          ((float*)Cv)[(size_t)row * N + col] = val;
                }
            }
        }
    }
}

// ---------------------------------------------------------------------------
// Small-tile bf16 MFMA GEMM for the output projection: C = A @ Bt^T + bias,
// fp32 out. 64x64 block tile, 4 waves (2x2, 32x32 each).
// Round 8: BK=64 (16 K-steps instead of 32 — halves barrier drains), same
// plane-split LDS trick. 1024 blocks = 4/CU; XCD-chunk swizzle kept.
// ---------------------------------------------------------------------------
__global__ __launch_bounds__(256) void gemm_bt_mfma64(
    const __bf16* __restrict__ A,   // [M,K]
    const __bf16* __restrict__ Bt,  // [N,K]
    const float* __restrict__ bias, // [N]
    float* __restrict__ C,          // [M,N]
    int M, int N, int K)
{
    __shared__ __align__(16) __bf16 As[2 * 64 * 32];    // [kk][row][32]
    __shared__ __align__(16) __bf16 Bs[2 * 64 * 32];

    const int tid  = threadIdx.x;
    const int lane = tid & 63;
    const int wave = tid >> 6;
    const int wm = (wave >> 1) * 32;
    const int wn = (wave & 1) * 32;

    const int hw  = (int)(blockIdx.x + gridDim.x * blockIdx.y);
    const int cpx = (int)gridDim.x >> 3;
    const int xcd = hw & 7;
    const int i_  = hw >> 3;
    const int n0 = (xcd * cpx + (i_ % cpx)) * 64;
    const int m0 = (i_ / cpx) * 64;

    const int lm = lane & 15;
    const int kq = lane >> 4;

    f32x4 acc[2][2] = {};

    for (int k0 = 0; k0 < K; k0 += 64) {
        __syncthreads();
        #pragma unroll
        for (int r = 0; r < 2; r++) {
            int flat = r * 256 + tid;            // 0..511
            int kk   = flat >> 8;
            int row  = (flat >> 2) & 63;
            int c4   = flat & 3;
            const char* ga = (const char*)(A + (size_t)(m0 + row) * K
                                             + k0 + kk * 32 + c4 * 8);
            char* la = (char*)As + flat * 16;
            __builtin_amdgcn_global_load_lds(
                (const __attribute__((address_space(1))) void*)ga,
                (__attribute__((address_space(3))) void*)la, 16, 0, 0);
            const char* gb = (const char*)(Bt + (size_t)(n0 + row) * K
                                              + k0 + kk * 32 + c4 * 8);
            char* lb = (char*)Bs + flat * 16;
            __builtin_amdgcn_global_load_lds(
                (const __attribute__((address_space(1))) void*)gb,
                (__attribute__((address_space(3))) void*)lb, 16, 0, 0);
        }
        __syncthreads();

        #pragma unroll
        for (int kk = 0; kk < 2; kk++) {
            bf16x8 af[2], bf[2];
            #pragma unroll
            for (int t = 0; t < 2; t++) {
                af[t] = *(const bf16x8*)&As[kk * 2048 + (wm + t * 16 + lm) * 32 + kq * 8];
                bf[t] = *(const bf16x8*)&Bs[kk * 2048 + (wn + t * 16 + lm) * 32 + kq * 8];
            }
            #pragma unroll
            for (int i = 0; i < 2; i++)
                #pragma unroll
                for (int j = 0; j < 2; j++)
                    acc[i][j] = __builtin_amdgcn_mfma_f32_16x16x32_bf16(
                        af[i], bf[j], acc[i][j], 0, 0, 0);
        }
    }

    const int r0 = kq * 4;
    #pragma unroll
    for (int i = 0; i < 2; i++) {
        #pragma unroll
        for (int j = 0; j < 2; j++) {
            int col = n0 + wn + j * 16 + lm;
            float bv = bias[col];
            #pragma unroll
            for (int r = 0; r < 4; r++) {
                int row = m0 + wm + i * 16 + r0 + r;
                C[(size_t)row * N + col] = acc[i][j][r] + bv;
            }
        }
    }
}

// ---------------------------------------------------------------------------
// K-parallel MFMA flash attention (causal), bf16 in/out, fp32 accum.
// Block = 256 threads = 4 waves; block owns 64 q-rows (4 frags/wave).
// Wave w processes k-tiles t = w, w+4, ... INDEPENDENTLY (no barriers in the
// k-loop) accumulating private unnormalized (O, l) — additive because the
// softmax has no running max (p = exp2(s), s pre-scaled by log2e/8, clamp).
// [Round 8: UNCHANGED control — best measured structure, 52.5-53.7 µs.]
//
// QK^T is computed SWAPPED: S^T = mfma(K_frag, Q_frag), so each lane holds
// P[q=c][k = jj*16 + quad*4 + r] — 4 CONSECUTIVE k of one q-row. These pack
// into one aligned 8-byte LDS store per (jj,qf) that lands exactly in the
// A-frag layout the PV readback needs (bank-uniform). Row-sums of l are
// lane-local + 2 cross-quad shuffles.
// End: 3-barrier LDS tree combine of the 4 waves' partials, then normalize.
// ---------------------------------------------------------------------------
__global__ __launch_bounds__(256) void attn_kpar_mfma(
    const __bf16* __restrict__ qkv, const __bf16* __restrict__ vt,
    __bf16* __restrict__ attn)
{
    // smem: loop phase = Pbuf[4 waves][4 qf][2048 B] = 32768 B
    //       combine    = Ored[2][64][66] f32 (33792 B) + lred[2][64] (512 B)
    __shared__ __align__(16) char smem[34304];

    const int tid  = threadIdx.x;
    const int wave = tid >> 6;
    const int lane = tid & 63;
    const int quad = lane >> 4;
    const int c    = lane & 15;

    const int bh = blockIdx.x;
    const int b  = bh >> 4;
    const int h  = bh & 15;
    const int qblk = (int)(gridDim.y - 1) - blockIdx.y;   // heavy first
    const int q0 = qblk * 64;

    const size_t base = (size_t)b * SEQ * QKV3;
    const int hoff = h * HDIM;
    const __bf16* vbase = vt + (size_t)bh * 64 * SEQ;

    // Q B-frags (pre-scaled by log2(e)/8 in the QKV GEMM epilogue)
    bf16x8 aq[4][2];
    #pragma unroll
    for (int qf = 0; qf < 4; qf++) {
        const __bf16* qrow = qkv + base +
            (size_t)(q0 + qf * 16 + c) * QKV3 + hoff + quad * 8;
        aq[qf][0] = *(const bf16x8*)(qrow);
        aq[qf][1] = *(const bf16x8*)(qrow + 32);
    }

    f32x4 acc[4][4] = {};      // [qf][dd], C-layout: col=d (lane&15), row=q (quad*4+r)
    float lpart[4] = {};       // per-lane row-sum partial for q = c (per qf)

    char* pbw = smem + wave * 8192;
    const int ntiles = qblk + 1;    // 64-k tiles covering [0, q0+63]

    for (int t = wave; t < ntiles; t += 4) {
        const int k0 = t * 64;
        const bool diag = (t == ntiles - 1);

        // S^T = K Q^T per jj (16 k-rows), exp2, pack 4 bf16 -> one b64 store
        #pragma unroll
        for (int jj = 0; jj < 4; jj++) {
            const __bf16* krow = qkv + base +
                (size_t)(k0 + jj * 16 + c) * QKV3 + EMBD + hoff + quad * 8;
            bf16x8 bk0 = *(const bf16x8*)(krow);
            bf16x8 bk1 = *(const bf16x8*)(krow + 32);
            const int kb = k0 + jj * 16 + quad * 4;   // this lane's k base (4 r's)
            const int wb = (jj >> 1) * 1024 + (((jj & 1) * 2 + (quad >> 1))) * 256
                         + c * 16 + (quad & 1) * 8;
            #pragma unroll
            for (int qf = 0; qf < 4; qf++) {
                f32x4 s = {};
                s = __builtin_amdgcn_mfma_f32_16x16x32_bf16(bk0, aq[qf][0], s, 0, 0, 0);
                s = __builtin_amdgcn_mfma_f32_16x16x32_bf16(bk1, aq[qf][1], s, 0, 0, 0);
                const int qa = q0 + qf * 16 + c;
                bf16x4 pk;
                #pragma unroll
                for (int r = 0; r < 4; r++) {
                    float p;
                    if (diag && (kb + r > qa)) p = 0.f;
                    else p = fast_exp2(fminf(s[r], SCLAMP));
                    lpart[qf] += p;
                    pk[r] = (__bf16)p;
                }
                *(bf16x4*)(pbw + qf * 2048 + wb) = pk;
            }
        }

        // O += P V : P A-frags from wave-private LDS (in-order per-wave pipe),
        // V^T B-frags direct from vt. Split by 32-k chunk to cap VGPR pressure.
        __builtin_amdgcn_s_setprio(1);
        #pragma unroll
        for (int kc = 0; kc < 2; kc++) {
            bf16x8 ap[4];
            #pragma unroll
            for (int qf = 0; qf < 4; qf++)
                ap[qf] = *(const bf16x8*)(pbw + qf * 2048 + kc * 1024 + lane * 16);
            #pragma unroll
            for (int dd = 0; dd < 4; dd++) {
                const __bf16* vr = vbase + (size_t)(dd * 16 + c) * SEQ
                                 + k0 + kc * 32 + quad * 8;
                bf16x8 bv = *(const bf16x8*)(vr);
                #pragma unroll
                for (int qf = 0; qf < 4; qf++)
                    acc[qf][dd] = __builtin_amdgcn_mfma_f32_16x16x32_bf16(
                        ap[qf], bv, acc[qf][dd], 0, 0, 0);
            }
        }
        __builtin_amdgcn_s_setprio(0);
    }

    // Full row-sums of l within wave: lane holds q=c partial; reduce across quads
    #pragma unroll
    for (int qf = 0; qf < 4; qf++) {
        float v = lpart[qf];
        v += __shfl_xor(v, 16);
        v += __shfl_xor(v, 32);
        lpart[qf] = v;
    }

    __syncthreads();   // done with Pbuf; reuse smem for the combine

    float* Ored = (float*)smem;                    // [2][64][66]
    float* lred = (float*)(smem + 33792);          // [2][64]

    if (wave < 2) {
        float* R = Ored + wave * (64 * 66);
        #pragma unroll
        for (int qf = 0; qf < 4; qf++) {
            #pragma unroll
            for (int dd = 0; dd < 4; dd++)
                #pragma unroll
                for (int r = 0; r < 4; r++)
                    R[(qf * 16 + quad * 4 + r) * 66 + dd * 16 + c] = acc[qf][dd][r];
            if (quad == 0) lred[wave * 64 + qf * 16 + c] = lpart[qf];
        }
    }
    __syncthreads();
    if (wave >= 2) {
        float* R = Ored + (wave - 2) * (64 * 66);
        #pragma unroll
        for (int qf = 0; qf < 4; qf++) {
            #pragma unroll
            for (int dd = 0; dd < 4; dd++)
                #pragma unroll
                for (int r = 0; r < 4; r++)
                    R[(qf * 16 + quad * 4 + r) * 66 + dd * 16 + c] += acc[qf][dd][r];
            if (quad == 0) lred[(wave - 2) * 64 + qf * 16 + c] += lpart[qf];
        }
    }
    __syncthreads();

    // Final: each thread does one 8-col chunk of one row; 2 iterations for 64 rows
    #pragma unroll
    for (int it = 0; it < 2; it++) {
        const int flat = it * 256 + tid;
        const int row = flat >> 3;         // 0..63
        const int cg  = flat & 7;          // 8-col group
        const float l = lred[row] + lred[64 + row];
        const float inv = 1.f / l;
        const float* R0 = Ored + row * 66 + cg * 8;
        const float* R1 = R0 + 64 * 66;
        bf16x8 o;
        #pragma unroll
        for (int i = 0; i < 8; i++) o[i] = (__bf16)((R0[i] + R1[i]) * inv);
        *(bf16x8*)&attn[((size_t)b * SEQ + q0 + row) * EMBD + hoff + cg * 8] = o;
    }
}

// ---------------------------------------------------------------------------
extern "C" void kernel_launch(void* const* d_in, const int* in_sizes, int n_in,
                              void* d_out, int out_size, void* d_ws, size_t ws_size,
                              hipStream_t stream)
{
    const float* x     = (const float*)d_in[0];  // [2,2048,1024]
    const float* W_qkv = (const float*)d_in[1];  // [1024,3072]
    const float* b_qkv = (const float*)d_in[2];  // [3072]
    const float* W_out = (const float*)d_in[3];  // [1024,1024]
    const float* b_out = (const float*)d_in[4];  // [1024]
    float* out = (float*)d_out;                  // [2,2048,1024] fp32

    const int M = BATCH * SEQ;   // 4096

    __bf16* xbf    = (__bf16*)d_ws;                          // [4096,1024]  8 MB
    __bf16* Wqkv_t = xbf    + (size_t)M * EMBD;              // [3072,1024]  6 MB
    __bf16* Wout_t = Wqkv_t + (size_t)QKV3 * EMBD;           // [1024,1024]  2 MB
    __bf16* qkv    = Wout_t + (size_t)EMBD * EMBD;           // [4096,3072] 24 MB
    __bf16* attn   = qkv    + (size_t)M * QKV3;              // [4096,1024]  8 MB
    __bf16* vtbuf  = attn   + (size_t)M * EMBD;              // [32,64,2048]  8 MB

    // 0) Fused prep: cast + both weight transposes in ONE dispatch
    prep_fused<<<3072, 256, 0, stream>>>(x, xbf, W_qkv, Wqkv_t, W_out, Wout_t);

    // 1) QKV projection (bf16 out; Q cols pre-scaled; V region written
    //    straight to vt[bh][d][k]); BK=64
    {
        dim3 grid(QKV3 / 128, M / 128);   // 24 x 32 = 768 blocks (%8 == 0)
        gemm_bt_mfma<true><<<grid, 256, 0, stream>>>(
            xbf, Wqkv_t, b_qkv, qkv, vtbuf, M, QKV3, EMBD, EMBD);
    }
    // 2) K-parallel MFMA flash causal attention (64 q/block, no loop barriers)
    {
        dim3 grid(BATCH * NHEAD, SEQ / 64);
        attn_kpar_mfma<<<grid, 256, 0, stream>>>(qkv, vtbuf, attn);
    }
    // 3) Output projection (fp32 out): 64x64 tiles, BK=64, XCD-chunk swizzled
    {
        dim3 grid(EMBD / 64, M / 64);     // 16 x 64 = 1024 blocks (%8 == 0)
        gemm_bt_mfma64<<<grid, 256, 0, stream>>>(attn, Wout_t, b_out, out, M, EMBD, EMBD);
    }
}